// Round 4
// baseline (769.079 us; speedup 1.0000x reference)
//
#include <hip/hip_runtime.h>
#include <stdint.h>

// Stage1Assigner (RPN matcher + subsample + top-k per GT) for MI355X.
// B=8 images, A=200000 anchors, G=64 GTs, K=4, thresholds 0.3/0.7, 128 max pos.
//
// PRNG: JAX threefry, jax_threefry_partitionable=True:
//   keys[b] = threefry2x32((0,42),(0,b));  bits[a] = y0^y1 of threefry2x32(key_b,(0,a))
// Selection of 128 positives = 128 lexicographically smallest (bits>>9, a).
//
// Single full IoU pass (k_top4_part): per-(slice, gt-half) partial top-4 AND
// per-anchor "any IoU>=0.7" bit (ballot -> posbits half-arrays; no init needed).
// k_top4_merge: merge partials -> top4/hq; anchors with val==hq (low-quality
// matches) atomicOr'd into posbitsA. argmax-gt is recomputed ONLY for the
// <=128 selected anchors in k_select (bit-identical IoU => same argmax).
// k_select (1 block/image): LDS hist -> target bin -> fine list -> exact
// 128th-smallest threshold -> per-gt counts (argmax recompute) -> outputs.
//
// IoU is fp-contract(off) IEEE per-op: identical bits across all passes and
// matches XLA per-HLO rounding.

#pragma clang fp contract(off)

#define B_IMG 8
#define A_N 200000
#define G_N 64
#define K_TOP 4
#define MAX_POS 128
#define FINE_CAP 4096
#define AS 2048
#define NS 98            // ceil(200000/2048)
#define NWORD 3136       // NS*32 u64 words of pos bits per image

typedef unsigned long long u64;
typedef unsigned int u32;

__device__ __forceinline__ u32 rotl32(u32 v, int n) { return (v << n) | (v >> (32 - n)); }

__device__ __forceinline__ void tf_round(u32& x0, u32& x1, int r) {
  x0 += x1; x1 = rotl32(x1, r); x1 ^= x0;
}

__device__ __forceinline__ void threefry2x32(u32 k0, u32 k1, u32& x0, u32& x1) {
  u32 ks2 = 0x1BD11BDAu ^ k0 ^ k1;
  x0 += k0; x1 += k1;
  tf_round(x0,x1,13); tf_round(x0,x1,15); tf_round(x0,x1,26); tf_round(x0,x1,6);
  x0 += k1; x1 += ks2 + 1u;
  tf_round(x0,x1,17); tf_round(x0,x1,29); tf_round(x0,x1,16); tf_round(x0,x1,24);
  x0 += ks2; x1 += k0 + 2u;
  tf_round(x0,x1,13); tf_round(x0,x1,15); tf_round(x0,x1,26); tf_round(x0,x1,6);
  x0 += k0; x1 += k1 + 3u;
  tf_round(x0,x1,17); tf_round(x0,x1,29); tf_round(x0,x1,16); tf_round(x0,x1,24);
  x0 += k1; x1 += ks2 + 4u;
  tf_round(x0,x1,13); tf_round(x0,x1,15); tf_round(x0,x1,26); tf_round(x0,x1,6);
  x0 += ks2; x1 += k0 + 5u;
}

__device__ __forceinline__ void image_key(int b, u32& kb0, u32& kb1) {
  u32 x0 = 0u, x1 = (u32)b;
  threefry2x32(0u, 42u, x0, x1);
  kb0 = x0; kb1 = x1;
}

__device__ __forceinline__ u32 rbits_for(u32 k0, u32 k1, u32 a) {
  u32 x0 = 0u, x1 = a;
  threefry2x32(k0, k1, x0, x1);
  return x0 ^ x1;
}

__device__ __forceinline__ void conv_box(float4 bx, float& x0, float& y0,
                                         float& x1, float& y1, float& area) {
  #pragma clang fp contract(off)
  x0 = bx.x - 0.5f * bx.z;
  y0 = bx.y - 0.5f * bx.w;
  x1 = bx.x + 0.5f * bx.z;
  y1 = bx.y + 0.5f * bx.w;
  area = (x1 - x0) * (y1 - y0);
}

__device__ __forceinline__ float iou_pair(float ax0, float ay0, float ax1, float ay1, float aarea,
                                          float gx0, float gy0, float gx1, float gy1, float garea) {
  #pragma clang fp contract(off)
  float ltx = fmaxf(gx0, ax0), lty = fmaxf(gy0, ay0);
  float rbx = fminf(gx1, ax1), rby = fminf(gy1, ay1);
  float w = fmaxf(rbx - ltx, 0.0f), h = fmaxf(rby - lty, 0.0f);
  float inter = w * h;
  float uni = (garea + aarea) - inter;
  return inter / uni;
}

__device__ __forceinline__ void top4_insert(u64 (&top)[4], u64 key) {
  if (key > top[3]) {
    if (key > top[0])      { top[3]=top[2]; top[2]=top[1]; top[1]=top[0]; top[0]=key; }
    else if (key > top[1]) { top[3]=top[2]; top[2]=top[1]; top[1]=key; }
    else if (key > top[2]) { top[3]=top[2]; top[2]=key; }
    else                   { top[3]=key; }
  }
}

__device__ __forceinline__ void wave_merge_top4(u64 (&top)[4]) {
  for (int off = 32; off >= 1; off >>= 1) {
    u64 o[4];
    #pragma unroll
    for (int k = 0; k < 4; k++) o[k] = __shfl_down(top[k], (unsigned)off);
    u64 m[4]; int i = 0, j = 0;
    #pragma unroll
    for (int k = 0; k < 4; k++) m[k] = (top[i] >= o[j]) ? top[i++] : o[j++];
    #pragma unroll
    for (int k = 0; k < 4; k++) top[k] = m[k];
  }
}

// ---------------- Kernel 1: per-(slice, b, gt-half) top-4 + ge0.7 bits ----------------
// grid (NS, B*2); block 256 = 4 waves; wave w handles gts {half*32 + w, +4, ...} (8 gts).
__launch_bounds__(256)
__global__ void k_top4_part(const float4* __restrict__ anchors, const float4* __restrict__ gt,
                            u64* __restrict__ partial,
                            u64* __restrict__ posA, u64* __restrict__ posB) {
  const int s = blockIdx.x;
  const int b = blockIdx.y >> 1, half = blockIdx.y & 1;
  const int t = threadIdx.x;
  const int wave = t >> 6, lane = t & 63;

  __shared__ float4 sxy[AS];        // converted xyxy (area recomputed inline)
  __shared__ float  sg[5][32];
  __shared__ u32    wm[256];

  const int base = s * AS;
  const int cnt = min(AS, A_N - base);
  const float4* ab = anchors + (size_t)b * A_N + base;

  for (int j = t; j < cnt; j += 256) {
    float x0, y0, x1, y1, ar;
    conv_box(ab[j], x0, y0, x1, y1, ar);
    sxy[j] = make_float4(x0, y0, x1, y1);
  }
  if (t < 32) {
    float x0, y0, x1, y1, ar;
    conv_box(gt[(size_t)b * G_N + half * 32 + t], x0, y0, x1, y1, ar);
    sg[0][t] = x0; sg[1][t] = y0; sg[2][t] = x1; sg[3][t] = y1; sg[4][t] = ar;
  }
  __syncthreads();

  u32 m = 0;   // bit k: anchor base+64k+lane has iou>=0.7 vs any of this thread's gts
  for (int gi = wave; gi < 32; gi += 4) {
    const int g = half * 32 + gi;
    const float gx0 = sg[0][gi], gy0 = sg[1][gi], gx1 = sg[2][gi], gy1 = sg[3][gi], ga = sg[4][gi];
    u64 top[4] = {0ull, 0ull, 0ull, 0ull};
    u32 t3hi = 0;
    u32 bit = 1u;
    for (int j = lane; j < cnt; j += 64, bit <<= 1) {
      float4 x = sxy[j];
      float aarea = (x.z - x.x) * (x.w - x.y);
      float v = iou_pair(x.x, x.y, x.z, x.w, aarea, gx0, gy0, gx1, gy1, ga);
      if (v >= 0.7f) m |= bit;
      u32 vb = __float_as_uint(v);
      if (vb >= t3hi) {                 // fast 32-bit pre-filter
        u64 key = ((u64)vb << 32) | (u64)(~(u32)(base + j));
        top4_insert(top, key);
        t3hi = (u32)(top[3] >> 32);
      }
    }
    wave_merge_top4(top);
    if (lane == 0) {
      u64* dst = partial + (((size_t)b * NS + s) * G_N + g) * 4;
      #pragma unroll
      for (int k = 0; k < 4; k++) dst[k] = top[k];
    }
  }

  wm[t] = m;
  __syncthreads();
  if (wave == 0) {
    u32 mc = wm[lane] | wm[64 + lane] | wm[128 + lane] | wm[192 + lane];
    u64* posH = half ? posB : posA;
    for (int k = 0; k < 32; k++) {
      u64 bal = __ballot((mc >> k) & 1u);
      if (lane == 0) posH[(size_t)b * NWORD + s * 32 + k] = bal;
    }
  }
}

// ---------------- Kernel 2: merge partials -> top4; lq anchors -> posA ----------------
__launch_bounds__(64)
__global__ void k_top4_merge(const u64* __restrict__ partial, u64* __restrict__ top4,
                             u64* __restrict__ posA) {
  const int b = blockIdx.y, g = blockIdx.x, lane = threadIdx.x;
  u64 top[4] = {0ull, 0ull, 0ull, 0ull};
  const u64* pb = partial + ((size_t)b * NS * G_N + g) * 4;
  for (int i = lane; i < NS * 4; i += 64) {
    u64 key = pb[(size_t)(i >> 2) * (G_N * 4) + (i & 3)];
    top4_insert(top, key);
  }
  wave_merge_top4(top);
  if (lane == 0) {
    u64* dst = top4 + ((size_t)b * G_N + g) * 4;
    #pragma unroll
    for (int k = 0; k < 4; k++) dst[k] = top[k];
  }
  // low-quality matches: every partial entry whose value bits == hq bits.
  u32 hqb = (u32)(__shfl(top[0], 0) >> 32);
  for (int i = lane; i < NS * 4; i += 64) {
    u64 key = pb[(size_t)(i >> 2) * (G_N * 4) + (i & 3)];
    u32 aidx = ~(u32)key;
    if ((u32)(key >> 32) == hqb && aidx < A_N)
      atomicOr(&posA[(size_t)b * NWORD + (aidx >> 6)], 1ull << (aidx & 63));
  }
}

// ---------------- Kernel 3: per-image selection + counts + output ----------------
__launch_bounds__(256)
__global__ void k_select(const float4* __restrict__ anchors, const float4* __restrict__ gt,
                         const u64* __restrict__ top4,
                         const u64* __restrict__ posA, const u64* __restrict__ posB,
                         float* __restrict__ out, int sec) {
  const int b = blockIdx.x;
  const int t = threadIdx.x;
  __shared__ u32 hist[4096];
  __shared__ u32 fine[FINE_CAP];
  __shared__ float sg[5][64];
  __shared__ u32 shq[64];
  __shared__ u32 red[256];
  __shared__ u32 scnt[64];
  __shared__ int sbin, sbefore;
  __shared__ u32 snpos, sfcnt;
  __shared__ u64 svT;

  for (int i = t; i < 4096; i += 256) hist[i] = 0;
  if (t < 64) {
    float x0, y0, x1, y1, ar;
    conv_box(gt[(size_t)b * G_N + t], x0, y0, x1, y1, ar);
    sg[0][t] = x0; sg[1][t] = y0; sg[2][t] = x1; sg[3][t] = y1; sg[4][t] = ar;
    shq[t] = (u32)(top4[((size_t)b * G_N + t) * 4] >> 32);
    scnt[t] = 0;
  }
  if (t == 0) { snpos = 0; sfcnt = 0; }
  u32 k0, k1; image_key(b, k0, k1);
  __syncthreads();

  const u64* pa = posA + (size_t)b * NWORD;
  const u64* pb = posB + (size_t)b * NWORD;

  // phase 1: npos + histogram of rbits>>20
  u32 npl = 0;
  for (int i = t; i < NWORD; i += 256) {
    u64 w = pa[i] | pb[i];
    npl += (u32)__popcll(w);
    while (w) {
      int bit = __ffsll((long long)w) - 1; w &= w - 1;
      u32 a = (u32)(i * 64 + bit);
      atomicAdd(&hist[rbits_for(k0, k1, a) >> 20], 1u);
    }
  }
  atomicAdd(&snpos, npl);
  __syncthreads();

  // phase 2: target bin
  u32 loc = 0;
  for (int j = 0; j < 16; j++) loc += hist[t * 16 + j];
  red[t] = loc;
  __syncthreads();
  if (t == 0) {
    if (snpos <= MAX_POS) { sbin = -1; sbefore = 0; }
    else {
      u32 cum = 0; int chunk = 0;
      for (int i = 0; i < 256; i++) {
        if (cum + red[i] >= MAX_POS) { chunk = i; break; }
        cum += red[i];
      }
      int tb = chunk * 16; u32 before = cum;
      for (int j = 0; j < 16; j++) {
        u32 h = hist[chunk * 16 + j];
        if (before + h >= MAX_POS) { tb = chunk * 16 + j; break; }
        before += h;
      }
      sbin = tb; sbefore = (int)before;
    }
  }
  __syncthreads();

  // phase 3: fine list + exact 128th-smallest threshold
  if (sbin >= 0) {
    const u32 binv = (u32)sbin;
    for (int i = t; i < NWORD; i += 256) {
      u64 w = pa[i] | pb[i];
      while (w) {
        int bit = __ffsll((long long)w) - 1; w &= w - 1;
        u32 a = (u32)(i * 64 + bit);
        u32 rb = rbits_for(k0, k1, a);
        if ((rb >> 20) == binv) {
          u32 idx = atomicAdd(&sfcnt, 1u);
          if (idx < FINE_CAP) fine[idx] = (((rb >> 9) & 0x7FFu) << 18) | a;
        }
      }
    }
    __syncthreads();
    const int m = min((int)sfcnt, FINE_CAP);
    const u32 need = (u32)(MAX_POS - sbefore);
    u32 lo = 0, hi = (1u << 29) - 1;
    while (lo < hi) {
      u32 mid = lo + ((hi - lo) >> 1);
      u32 c = 0;
      for (int j = t; j < m; j += 256) c += (fine[j] <= mid) ? 1u : 0u;
      red[t] = c;
      __syncthreads();
      for (int s = 128; s > 0; s >>= 1) { if (t < s) red[t] += red[t + s]; __syncthreads(); }
      c = red[0];
      __syncthreads();
      if (c >= need) hi = mid; else lo = mid + 1;   // uniform
    }
    if (t == 0) svT = ((u64)(u32)sbin << 29) | (u64)lo;
  } else if (t == 0) svT = ~0ull;
  __syncthreads();

  // phase 4: per-gt counts (argmax recomputed only for selected anchors)
  const u64 T = svT;
  const float4* ab = anchors + (size_t)b * A_N;
  for (int i = t; i < NWORD; i += 256) {
    u64 w = pa[i] | pb[i];
    while (w) {
      int bit = __ffsll((long long)w) - 1; w &= w - 1;
      u32 a = (u32)(i * 64 + bit);
      bool sel = true;
      if (T != ~0ull) {
        u32 rb = rbits_for(k0, k1, a);
        sel = ((((u64)(rb >> 9)) << 18) | (u64)a) <= T;
      }
      if (sel) {
        float ax0, ay0, ax1, ay1, aar;
        conv_box(ab[a], ax0, ay0, ax1, ay1, aar);
        float bv = -1.0f; int g0 = 0;
        for (int g = 0; g < 64; g++) {
          float v = iou_pair(ax0, ay0, ax1, ay1, aar,
                             sg[0][g], sg[1][g], sg[2][g], sg[3][g], sg[4][g]);
          if (v > bv) { bv = v; g0 = g; }   // strict > = first max (jnp.argmax)
        }
        atomicAdd(&scnt[g0], 1u);
      }
    }
  }
  __syncthreads();

  // phase 5: outputs
  if (t < 64) {
    const int g = t;
    const u32 c = min(scnt[g], (u32)K_TOP);
    const u64* t4 = top4 + ((size_t)b * G_N + g) * 4;
    #pragma unroll
    for (int k = 0; k < 4; k++) {
      u64 key = t4[k];
      u32 fb = (u32)(key >> 32);
      u32 aidx = ~(u32)key;
      bool valid = (u32)k < c;
      int o = b * (G_N * K_TOP) + g * K_TOP + k;
      out[0 * sec + o] = valid ? (float)aidx : -1.0f;          // pr_inds
      out[1 * sec + o] = valid ? (float)g : -1.0f;             // gt_inds
      out[2 * sec + o] = valid ? 1.0f : 0.0f;                  // valid mask
      out[3 * sec + o] = valid ? __uint_as_float(fb) : 0.0f;   // topk ious
    }
  }
}

extern "C" void kernel_launch(void* const* d_in, const int* in_sizes, int n_in,
                              void* d_out, int out_size, void* d_ws, size_t ws_size,
                              hipStream_t stream) {
  const float4* anchors = (const float4*)d_in[0];  // [B, A, 4] cxcywh
  const float4* gt      = (const float4*)d_in[1];  // [B, G, 4] cxcywh
  float* out = (float*)d_out;                      // 4 x [B, G*K] concatenated

  // All buffers fully written by kernels before any read -> no memset needed.
  char* ws = (char*)d_ws;
  u64* top4    = (u64*)(ws);                       // 16384 B
  u64* partial = (u64*)(ws + 16384);               // B*NS*G*4*8 = 1605632 B
  u64* posA    = (u64*)(ws + 1622016);             // B*NWORD*8 = 200704 B
  u64* posB    = (u64*)(ws + 1822720);             // 200704 B   (total ~1.93 MB)

  int sec = out_size / 4;  // 2048 = B*G*K

  k_top4_part <<<dim3(NS, B_IMG * 2), 256, 0, stream>>>(anchors, gt, partial, posA, posB);
  k_top4_merge<<<dim3(G_N, B_IMG), 64, 0, stream>>>(partial, top4, posA);
  k_select    <<<dim3(B_IMG), 256, 0, stream>>>(anchors, gt, top4, posA, posB, out, sec);
}

// Round 5
// 706.877 us; speedup vs baseline: 1.0880x; 1.0880x over previous
//
#include <hip/hip_runtime.h>
#include <stdint.h>

// Stage1Assigner (RPN matcher + subsample + top-k per GT) for MI355X.
// B=8 images, A=200000 anchors, G=64 GTs, K=4, thresholds 0.3/0.7, 128 max pos.
//
// PRNG: JAX threefry, jax_threefry_partitionable=True:
//   keys[b] = threefry2x32((0,42),(0,b));  bits[a] = y0^y1 of threefry2x32(key_b,(0,a))
// Selection of 128 positives = 128 lexicographically smallest (bits>>9, a).
//
// Single full IoU pass (k_top4_part): per-(slice, gt-half, 2-gt-paired) partial
// top-4 AND per-anchor "any IoU>=0.7" bit -> shared pos-bit array via atomicOr;
// first setter of a bit (dedup on returned old) adds to npos + 4096-bin hist of
// rbits>>20. k_top4_merge: partials -> top4/hq; low-quality anchors (val==hq)
// atomicOr'd with same dedup. Tail: k_bin (target bin), k_collect (fine keys of
// target bin), k_tstar (exact 128th-smallest threshold, 1 wave/img), k_count
// (argmax-gt recomputed ONLY for <=128 selected anchors), k_out.
//
// IoU is fp-contract(off) IEEE per-op: identical bits across all passes and
// matches XLA per-HLO rounding.

#pragma clang fp contract(off)

#define B_IMG 8
#define A_N 200000
#define G_N 64
#define K_TOP 4
#define MAX_POS 128
#define FINE_CAP 4096
#define AS 2048
#define NS 98            // ceil(200000/2048)
#define NWORD 3136       // NS*32 u64 words of pos bits per image

typedef unsigned long long u64;
typedef unsigned int u32;

__device__ __forceinline__ u32 rotl32(u32 v, int n) { return (v << n) | (v >> (32 - n)); }

__device__ __forceinline__ void tf_round(u32& x0, u32& x1, int r) {
  x0 += x1; x1 = rotl32(x1, r); x1 ^= x0;
}

__device__ __forceinline__ void threefry2x32(u32 k0, u32 k1, u32& x0, u32& x1) {
  u32 ks2 = 0x1BD11BDAu ^ k0 ^ k1;
  x0 += k0; x1 += k1;
  tf_round(x0,x1,13); tf_round(x0,x1,15); tf_round(x0,x1,26); tf_round(x0,x1,6);
  x0 += k1; x1 += ks2 + 1u;
  tf_round(x0,x1,17); tf_round(x0,x1,29); tf_round(x0,x1,16); tf_round(x0,x1,24);
  x0 += ks2; x1 += k0 + 2u;
  tf_round(x0,x1,13); tf_round(x0,x1,15); tf_round(x0,x1,26); tf_round(x0,x1,6);
  x0 += k0; x1 += k1 + 3u;
  tf_round(x0,x1,17); tf_round(x0,x1,29); tf_round(x0,x1,16); tf_round(x0,x1,24);
  x0 += k1; x1 += ks2 + 4u;
  tf_round(x0,x1,13); tf_round(x0,x1,15); tf_round(x0,x1,26); tf_round(x0,x1,6);
  x0 += ks2; x1 += k0 + 5u;
}

__device__ __forceinline__ void image_key(int b, u32& kb0, u32& kb1) {
  u32 x0 = 0u, x1 = (u32)b;
  threefry2x32(0u, 42u, x0, x1);
  kb0 = x0; kb1 = x1;
}

__device__ __forceinline__ u32 rbits_for(u32 k0, u32 k1, u32 a) {
  u32 x0 = 0u, x1 = a;
  threefry2x32(k0, k1, x0, x1);
  return x0 ^ x1;
}

__device__ __forceinline__ void conv_box(float4 bx, float& x0, float& y0,
                                         float& x1, float& y1, float& area) {
  #pragma clang fp contract(off)
  x0 = bx.x - 0.5f * bx.z;
  y0 = bx.y - 0.5f * bx.w;
  x1 = bx.x + 0.5f * bx.z;
  y1 = bx.y + 0.5f * bx.w;
  area = (x1 - x0) * (y1 - y0);
}

__device__ __forceinline__ float iou_pair(float ax0, float ay0, float ax1, float ay1, float aarea,
                                          float gx0, float gy0, float gx1, float gy1, float garea) {
  #pragma clang fp contract(off)
  float ltx = fmaxf(gx0, ax0), lty = fmaxf(gy0, ay0);
  float rbx = fminf(gx1, ax1), rby = fminf(gy1, ay1);
  float w = fmaxf(rbx - ltx, 0.0f), h = fmaxf(rby - lty, 0.0f);
  float inter = w * h;
  float uni = (garea + aarea) - inter;
  return inter / uni;
}

__device__ __forceinline__ void top4_insert(u64 (&top)[4], u64 key) {
  if (key > top[3]) {
    if (key > top[0])      { top[3]=top[2]; top[2]=top[1]; top[1]=top[0]; top[0]=key; }
    else if (key > top[1]) { top[3]=top[2]; top[2]=top[1]; top[1]=key; }
    else if (key > top[2]) { top[3]=top[2]; top[2]=key; }
    else                   { top[3]=key; }
  }
}

__device__ __forceinline__ void wave_merge_top4(u64 (&top)[4]) {
  for (int off = 32; off >= 1; off >>= 1) {
    u64 o[4];
    #pragma unroll
    for (int k = 0; k < 4; k++) o[k] = __shfl_down(top[k], (unsigned)off);
    u64 m[4]; int i = 0, j = 0;
    #pragma unroll
    for (int k = 0; k < 4; k++) m[k] = (top[i] >= o[j]) ? top[i++] : o[j++];
    #pragma unroll
    for (int k = 0; k < 4; k++) top[k] = m[k];
  }
}

// ---------------- Kernel 1: per-(slice, b, gt-half) top-4 + pos bits + hist ----------------
// grid (NS, B*2); block 256 = 4 waves; wave w handles gt-pairs {w, w+4, w+8, w+12} of its half.
__launch_bounds__(256, 4)
__global__ void k_top4_part(const float4* __restrict__ anchors, const float4* __restrict__ gt,
                            u64* __restrict__ partial, u64* __restrict__ pos,
                            u32* __restrict__ npos, u32* __restrict__ hist) {
  const int s = blockIdx.x;
  const int b = blockIdx.y >> 1, half = blockIdx.y & 1;
  const int t = threadIdx.x;
  const int wave = t >> 6, lane = t & 63;

  __shared__ float4 sxy[AS];        // converted xyxy (area recomputed inline)
  __shared__ float  sg[5][32];
  __shared__ u32    wm[256];

  const int base = s * AS;
  const int cnt = min(AS, A_N - base);
  const float4* ab = anchors + (size_t)b * A_N + base;

  for (int j = t; j < cnt; j += 256) {
    float x0, y0, x1, y1, ar;
    conv_box(ab[j], x0, y0, x1, y1, ar);
    sxy[j] = make_float4(x0, y0, x1, y1);
  }
  if (t < 32) {
    float x0, y0, x1, y1, ar;
    conv_box(gt[(size_t)b * G_N + half * 32 + t], x0, y0, x1, y1, ar);
    sg[0][t] = x0; sg[1][t] = y0; sg[2][t] = x1; sg[3][t] = y1; sg[4][t] = ar;
  }
  __syncthreads();

  u32 m = 0;   // bit k: anchor base+64k+lane has iou>=0.7 vs any of this block's gts
  for (int gp = wave; gp < 16; gp += 4) {
    const int gi = gp * 2;
    const float ax = sg[0][gi],   ay = sg[1][gi],   az = sg[2][gi],   aw = sg[3][gi],   aa = sg[4][gi];
    const float bx = sg[0][gi+1], by = sg[1][gi+1], bz = sg[2][gi+1], bw = sg[3][gi+1], ba = sg[4][gi+1];
    u64 topA[4] = {0ull, 0ull, 0ull, 0ull};
    u64 topB[4] = {0ull, 0ull, 0ull, 0ull};
    u32 hiA = 0, hiB = 0;
    u32 bit = 1u;
    for (int j = lane; j < cnt; j += 64, bit <<= 1) {
      float4 x = sxy[j];
      float aarea = (x.z - x.x) * (x.w - x.y);
      float v0 = iou_pair(x.x, x.y, x.z, x.w, aarea, ax, ay, az, aw, aa);
      float v1 = iou_pair(x.x, x.y, x.z, x.w, aarea, bx, by, bz, bw, ba);
      if (fmaxf(v0, v1) >= 0.7f) m |= bit;
      u32 vb0 = __float_as_uint(v0), vb1 = __float_as_uint(v1);
      u32 ni = ~(u32)(base + j);
      if (vb0 >= hiA) { top4_insert(topA, ((u64)vb0 << 32) | (u64)ni); hiA = (u32)(topA[3] >> 32); }
      if (vb1 >= hiB) { top4_insert(topB, ((u64)vb1 << 32) | (u64)ni); hiB = (u32)(topB[3] >> 32); }
    }
    wave_merge_top4(topA);
    wave_merge_top4(topB);
    if (lane == 0) {
      const int g = half * 32 + gi;
      u64* dst = partial + (((size_t)b * NS + s) * G_N + g) * 4;
      #pragma unroll
      for (int k = 0; k < 4; k++) { dst[k] = topA[k]; dst[4 + k] = topB[k]; }
    }
  }

  wm[t] = m;
  __syncthreads();
  if (wave == 0) {
    u32 k0, k1; image_key(b, k0, k1);
    u32 mc = wm[lane] | wm[64 + lane] | wm[128 + lane] | wm[192 + lane];
    u64* posb = pos + (size_t)b * NWORD + s * 32;
    for (int k = 0; k < 32; k++) {
      u64 bal = __ballot((mc >> k) & 1u);
      u64 nb = 0;
      if (lane == 0 && bal) {
        u64 old = atomicOr(&posb[k], bal);
        nb = bal & ~old;
        if (nb) atomicAdd(&npos[b], (u32)__popcll(nb));
      }
      nb = __shfl(nb, 0);
      if ((nb >> lane) & 1ull) {
        u32 a = (u32)(base + k * 64 + lane);
        u32 rb = rbits_for(k0, k1, a);
        atomicAdd(&hist[b * 4096 + (rb >> 20)], 1u);
      }
    }
  }
}

// ---------------- Kernel 2: merge partials -> top4; lq anchors -> pos (dedup'd) ----------------
__launch_bounds__(64)
__global__ void k_top4_merge(const u64* __restrict__ partial, u64* __restrict__ top4,
                             u64* __restrict__ pos, u32* __restrict__ npos,
                             u32* __restrict__ hist) {
  const int b = blockIdx.y, g = blockIdx.x, lane = threadIdx.x;
  u64 top[4] = {0ull, 0ull, 0ull, 0ull};
  const u64* pb = partial + ((size_t)b * NS * G_N + g) * 4;
  for (int i = lane; i < NS * 4; i += 64) {
    u64 key = pb[(size_t)(i >> 2) * (G_N * 4) + (i & 3)];
    top4_insert(top, key);
  }
  wave_merge_top4(top);
  if (lane == 0) {
    u64* dst = top4 + ((size_t)b * G_N + g) * 4;
    #pragma unroll
    for (int k = 0; k < 4; k++) dst[k] = top[k];
  }
  // low-quality matches: every partial entry whose value bits == hq bits.
  u32 hqb = (u32)(__shfl(top[0], 0) >> 32);
  u32 k0, k1; image_key(b, k0, k1);
  for (int i = lane; i < NS * 4; i += 64) {
    u64 key = pb[(size_t)(i >> 2) * (G_N * 4) + (i & 3)];
    u32 aidx = ~(u32)key;
    if ((u32)(key >> 32) == hqb && aidx < A_N) {
      u64 bit = 1ull << (aidx & 63);
      u64 old = atomicOr(&pos[(size_t)b * NWORD + (aidx >> 6)], bit);
      if (!(old & bit)) {
        atomicAdd(&npos[b], 1u);
        u32 rb = rbits_for(k0, k1, aidx);
        atomicAdd(&hist[b * 4096 + (rb >> 20)], 1u);
      }
    }
  }
}

// ---------------- Kernel 3: per-image target bin ----------------
__launch_bounds__(256)
__global__ void k_bin(const u32* __restrict__ npos, const u32* __restrict__ hist,
                      int2* __restrict__ binsel) {
  const int b = blockIdx.x;
  const int t = threadIdx.x;
  __shared__ u32 part[256];
  const u32* hb = hist + b * 4096;
  u32 local = 0;
  for (int j = 0; j < 16; j++) local += hb[t * 16 + j];
  part[t] = local;
  __syncthreads();
  if (t == 0) {
    if (npos[b] <= MAX_POS) {
      binsel[b] = make_int2(-1, 0);
    } else {
      u32 cum = 0; int chunk = 0;
      for (int i = 0; i < 256; i++) {
        if (cum + part[i] >= MAX_POS) { chunk = i; break; }
        cum += part[i];
      }
      int tb = chunk * 16; u32 before = cum;
      for (int j = 0; j < 16; j++) {
        u32 h = hb[chunk * 16 + j];
        if (before + h >= MAX_POS) { tb = chunk * 16 + j; break; }
        before += h;
      }
      binsel[b] = make_int2(tb, (int)before);
    }
  }
}

// ---------------- Kernel 4: collect fine candidates in target bin ----------------
// grid (NS, B): block handles 2048 anchors, anchor-parallel (no divergent bit loops).
__launch_bounds__(256)
__global__ void k_collect(const u64* __restrict__ pos, const int2* __restrict__ binsel,
                          u32* __restrict__ fine, u32* __restrict__ fcnt) {
  const int b = blockIdx.y;
  const int stb = binsel[b].x;
  if (stb < 0) return;
  u32 k0, k1; image_key(b, k0, k1);
  const int a0 = blockIdx.x * AS;
  const u64* pw = pos + (size_t)b * NWORD;
  for (int j = threadIdx.x; j < AS; j += 256) {
    int a = a0 + j;
    if (a >= A_N) break;
    if (!((pw[a >> 6] >> (a & 63)) & 1ull)) continue;
    u32 rb = rbits_for(k0, k1, (u32)a);
    if ((int)(rb >> 20) != stb) continue;
    u32 idx = atomicAdd(&fcnt[b], 1u);
    if (idx < FINE_CAP) fine[b * FINE_CAP + idx] = (((rb >> 9) & 0x7FFu) << 18) | (u32)a;
  }
}

// ---------------- Kernel 5: exact 128th-smallest threshold (1 wave/image) ----------------
__launch_bounds__(64)
__global__ void k_tstar(const int2* __restrict__ binsel, const u32* __restrict__ fine,
                        const u32* __restrict__ fcnt, u64* __restrict__ Tstar) {
  const int b = blockIdx.x;
  const int lane = threadIdx.x;
  int2 bs = binsel[b];
  if (bs.x < 0) { if (lane == 0) Tstar[b] = ~0ull; return; }
  const int m = min((int)fcnt[b], FINE_CAP);
  const u32 need = (u32)(MAX_POS - bs.y);   // >= 1
  const u32* fb = fine + b * FINE_CAP;
  u32 lo = 0, hi = (1u << 29) - 1;
  while (lo < hi) {
    u32 mid = lo + ((hi - lo) >> 1);
    u32 c = 0;
    for (int j = lane; j < m; j += 64) c += (fb[j] <= mid) ? 1u : 0u;
    #pragma unroll
    for (int off = 32; off >= 1; off >>= 1) c += __shfl_xor(c, off);
    if (c >= need) hi = mid; else lo = mid + 1;   // uniform across wave
  }
  if (lane == 0) Tstar[b] = ((u64)(u32)bs.x << 29) | (u64)lo;   // 41-bit threshold
}

// ---------------- Kernel 6: per-gt counts (argmax only for selected) ----------------
__launch_bounds__(256)
__global__ void k_count(const float4* __restrict__ anchors, const float4* __restrict__ gt,
                        const u64* __restrict__ pos, const u64* __restrict__ Tstar,
                        u32* __restrict__ cnt) {
  const int b = blockIdx.y;
  const int t = threadIdx.x;
  __shared__ float sg[5][64];
  if (t < 64) {
    float x0, y0, x1, y1, ar;
    conv_box(gt[(size_t)b * G_N + t], x0, y0, x1, y1, ar);
    sg[0][t] = x0; sg[1][t] = y0; sg[2][t] = x1; sg[3][t] = y1; sg[4][t] = ar;
  }
  __syncthreads();
  u32 k0, k1; image_key(b, k0, k1);
  const u64 T = Tstar[b];
  const int a0 = blockIdx.x * AS;
  const u64* pw = pos + (size_t)b * NWORD;
  const float4* ab = anchors + (size_t)b * A_N;
  for (int j = t; j < AS; j += 256) {
    int a = a0 + j;
    if (a >= A_N) break;
    if (!((pw[a >> 6] >> (a & 63)) & 1ull)) continue;
    if (T != ~0ull) {
      u32 rb = rbits_for(k0, k1, (u32)a);
      if (((((u64)(rb >> 9)) << 18) | (u64)(u32)a) > T) continue;
    }
    float ax0, ay0, ax1, ay1, aar;
    conv_box(ab[a], ax0, ay0, ax1, ay1, aar);
    float bv = -1.0f; int g0 = 0;
    for (int g = 0; g < 64; g++) {
      float v = iou_pair(ax0, ay0, ax1, ay1, aar,
                         sg[0][g], sg[1][g], sg[2][g], sg[3][g], sg[4][g]);
      if (v > bv) { bv = v; g0 = g; }   // strict > = first max (jnp.argmax)
    }
    atomicAdd(&cnt[b * G_N + g0], 1u);
  }
}

// ---------------- Kernel 7: output ----------------
__launch_bounds__(64)
__global__ void k_out(const u64* __restrict__ top4, const u32* __restrict__ cnt,
                      float* __restrict__ out, int sec) {
  const int b = blockIdx.x;
  const int g = threadIdx.x;   // 64 threads
  const u32 c = min(cnt[b * G_N + g], (u32)K_TOP);
  const u64* t4 = top4 + ((size_t)b * G_N + g) * 4;
  #pragma unroll
  for (int k = 0; k < 4; k++) {
    u64 key = t4[k];
    u32 fb = (u32)(key >> 32);
    u32 aidx = ~(u32)key;
    bool valid = (u32)k < c;
    int o = b * (G_N * K_TOP) + g * K_TOP + k;
    out[0 * sec + o] = valid ? (float)aidx : -1.0f;          // pr_inds
    out[1 * sec + o] = valid ? (float)g : -1.0f;             // gt_inds
    out[2 * sec + o] = valid ? 1.0f : 0.0f;                  // valid mask
    out[3 * sec + o] = valid ? __uint_as_float(fb) : 0.0f;   // topk ious
  }
}

extern "C" void kernel_launch(void* const* d_in, const int* in_sizes, int n_in,
                              void* d_out, int out_size, void* d_ws, size_t ws_size,
                              hipStream_t stream) {
  const float4* anchors = (const float4*)d_in[0];  // [B, A, 4] cxcywh
  const float4* gt      = (const float4*)d_in[1];  // [B, G, 4] cxcywh
  float* out = (float*)d_out;                      // 4 x [B, G*K] concatenated

  // Layout (total 1,955,904 B):
  //   top4    @ 0         (16,384)
  //   partial @ 16,384    (1,605,632) — dead after k_top4_merge; aliased by:
  //       fine   @ 16,384   (131,072)
  //       binsel @ 147,456  (64)
  //       Tstar  @ 147,520  (64)
  //   zeroed  @ 1,622,016 (333,888): pos(200,704) hist(131,072) npos(32) fcnt(32) cnt(2,048)
  char* ws = (char*)d_ws;
  u64*  top4    = (u64*)(ws);
  u64*  partial = (u64*)(ws + 16384);
  u32*  fine    = (u32*)(ws + 16384);
  int2* binsel  = (int2*)(ws + 147456);
  u64*  Tstar   = (u64*)(ws + 147520);
  char* zr      = ws + 1622016;
  u64*  pos     = (u64*)(zr);
  u32*  hist    = (u32*)(zr + 200704);
  u32*  npos    = (u32*)(zr + 331776);
  u32*  fcnt    = (u32*)(zr + 331808);
  u32*  cnt     = (u32*)(zr + 331840);

  hipMemsetAsync(zr, 0, 333888, stream);

  int sec = out_size / 4;  // 2048 = B*G*K

  k_top4_part <<<dim3(NS, B_IMG * 2), 256, 0, stream>>>(anchors, gt, partial, pos, npos, hist);
  k_top4_merge<<<dim3(G_N, B_IMG), 64, 0, stream>>>(partial, top4, pos, npos, hist);
  k_bin       <<<dim3(B_IMG), 256, 0, stream>>>(npos, hist, binsel);
  k_collect   <<<dim3(NS, B_IMG), 256, 0, stream>>>(pos, binsel, fine, fcnt);
  k_tstar     <<<dim3(B_IMG), 64, 0, stream>>>(binsel, fine, fcnt, Tstar);
  k_count     <<<dim3(NS, B_IMG), 256, 0, stream>>>(anchors, gt, pos, Tstar, cnt);
  k_out       <<<dim3(B_IMG), 64, 0, stream>>>(top4, cnt, out, sec);
}

// Round 6
// 364.418 us; speedup vs baseline: 2.1104x; 1.9397x over previous
//
#include <hip/hip_runtime.h>
#include <stdint.h>

// Stage1Assigner (RPN matcher + subsample + top-k per GT) for MI355X.
// B=8 images, A=200000 anchors, G=64 GTs, K=4, thresholds 0.3/0.7, 128 max pos.
//
// PRNG: JAX threefry, jax_threefry_partitionable=True:
//   keys[b] = threefry2x32((0,42),(0,b));  bits[a] = y0^y1 of threefry2x32(key_b,(0,a))
// Selection of 128 positives = 128 lexicographically smallest (bits>>9, a).
//
// k_top4_part: single full IoU pass, 4-GT-paired; per-(slice,gt) partial top-4
//   + per-anchor "any IoU>=0.7" ballot -> PLAIN stores into posA/posB halves
//   (no atomics in the hot kernel — R4's in-kernel atomic epilogue was a 2x
//   regression: serial lane-0 atomic chains + L2 line thrash).
// k_top4_merge: partials -> top4/hq; low-quality anchors (val==hq) atomicOr.
// k_hist: 1 block/image, LDS histogram (4096 bins of rbits>>20) + npos.
// k_bin/k_collect/k_tstar: exact 128th-smallest threshold via bin + fine list.
// k_count: argmax-gt recomputed ONLY for <=128 selected anchors. k_out: emit.
//
// IoU is fp-contract(off) IEEE per-op: identical bits across all passes and
// matches XLA per-HLO rounding.

#pragma clang fp contract(off)

#define B_IMG 8
#define A_N 200000
#define G_N 64
#define K_TOP 4
#define MAX_POS 128
#define FINE_CAP 4096
#define AS 2048
#define NS 98            // ceil(200000/2048)
#define NWORD 3136       // NS*32 u64 words of pos bits per image

typedef unsigned long long u64;
typedef unsigned int u32;

__device__ __forceinline__ u32 rotl32(u32 v, int n) { return (v << n) | (v >> (32 - n)); }

__device__ __forceinline__ void tf_round(u32& x0, u32& x1, int r) {
  x0 += x1; x1 = rotl32(x1, r); x1 ^= x0;
}

__device__ __forceinline__ void threefry2x32(u32 k0, u32 k1, u32& x0, u32& x1) {
  u32 ks2 = 0x1BD11BDAu ^ k0 ^ k1;
  x0 += k0; x1 += k1;
  tf_round(x0,x1,13); tf_round(x0,x1,15); tf_round(x0,x1,26); tf_round(x0,x1,6);
  x0 += k1; x1 += ks2 + 1u;
  tf_round(x0,x1,17); tf_round(x0,x1,29); tf_round(x0,x1,16); tf_round(x0,x1,24);
  x0 += ks2; x1 += k0 + 2u;
  tf_round(x0,x1,13); tf_round(x0,x1,15); tf_round(x0,x1,26); tf_round(x0,x1,6);
  x0 += k0; x1 += k1 + 3u;
  tf_round(x0,x1,17); tf_round(x0,x1,29); tf_round(x0,x1,16); tf_round(x0,x1,24);
  x0 += k1; x1 += ks2 + 4u;
  tf_round(x0,x1,13); tf_round(x0,x1,15); tf_round(x0,x1,26); tf_round(x0,x1,6);
  x0 += ks2; x1 += k0 + 5u;
}

__device__ __forceinline__ void image_key(int b, u32& kb0, u32& kb1) {
  u32 x0 = 0u, x1 = (u32)b;
  threefry2x32(0u, 42u, x0, x1);
  kb0 = x0; kb1 = x1;
}

__device__ __forceinline__ u32 rbits_for(u32 k0, u32 k1, u32 a) {
  u32 x0 = 0u, x1 = a;
  threefry2x32(k0, k1, x0, x1);
  return x0 ^ x1;
}

__device__ __forceinline__ void conv_box(float4 bx, float& x0, float& y0,
                                         float& x1, float& y1, float& area) {
  #pragma clang fp contract(off)
  x0 = bx.x - 0.5f * bx.z;
  y0 = bx.y - 0.5f * bx.w;
  x1 = bx.x + 0.5f * bx.z;
  y1 = bx.y + 0.5f * bx.w;
  area = (x1 - x0) * (y1 - y0);
}

__device__ __forceinline__ float iou_pair(float ax0, float ay0, float ax1, float ay1, float aarea,
                                          float gx0, float gy0, float gx1, float gy1, float garea) {
  #pragma clang fp contract(off)
  float ltx = fmaxf(gx0, ax0), lty = fmaxf(gy0, ay0);
  float rbx = fminf(gx1, ax1), rby = fminf(gy1, ay1);
  float w = fmaxf(rbx - ltx, 0.0f), h = fmaxf(rby - lty, 0.0f);
  float inter = w * h;
  float uni = (garea + aarea) - inter;
  return inter / uni;
}

__device__ __forceinline__ void top4_insert(u64 (&top)[4], u64 key) {
  if (key > top[3]) {
    if (key > top[0])      { top[3]=top[2]; top[2]=top[1]; top[1]=top[0]; top[0]=key; }
    else if (key > top[1]) { top[3]=top[2]; top[2]=top[1]; top[1]=key; }
    else if (key > top[2]) { top[3]=top[2]; top[2]=key; }
    else                   { top[3]=key; }
  }
}

__device__ __forceinline__ void wave_merge_top4(u64 (&top)[4]) {
  for (int off = 32; off >= 1; off >>= 1) {
    u64 o[4];
    #pragma unroll
    for (int k = 0; k < 4; k++) o[k] = __shfl_down(top[k], (unsigned)off);
    u64 m[4]; int i = 0, j = 0;
    #pragma unroll
    for (int k = 0; k < 4; k++) m[k] = (top[i] >= o[j]) ? top[i++] : o[j++];
    #pragma unroll
    for (int k = 0; k < 4; k++) top[k] = m[k];
  }
}

// ---------------- Kernel 1: per-(slice, b, gt-half) top-4 + pos-bit ballot ----------------
// grid (NS, B*2); block 256 = 4 waves; wave w handles 4-gt groups {w, w+4} of its half.
__launch_bounds__(256, 4)
__global__ void k_top4_part(const float4* __restrict__ anchors, const float4* __restrict__ gt,
                            u64* __restrict__ partial,
                            u64* __restrict__ posA, u64* __restrict__ posB) {
  const int s = blockIdx.x;
  const int b = blockIdx.y >> 1, half = blockIdx.y & 1;
  const int t = threadIdx.x;
  const int wave = t >> 6, lane = t & 63;

  __shared__ float4 sxy[AS];        // converted xyxy (area recomputed inline)
  __shared__ float  sg[5][32];
  __shared__ u32    wm[256];

  const int base = s * AS;
  const int cnt = min(AS, A_N - base);
  const float4* ab = anchors + (size_t)b * A_N + base;

  for (int j = t; j < cnt; j += 256) {
    float x0, y0, x1, y1, ar;
    conv_box(ab[j], x0, y0, x1, y1, ar);
    sxy[j] = make_float4(x0, y0, x1, y1);
  }
  if (t < 32) {
    float x0, y0, x1, y1, ar;
    conv_box(gt[(size_t)b * G_N + half * 32 + t], x0, y0, x1, y1, ar);
    sg[0][t] = x0; sg[1][t] = y0; sg[2][t] = x1; sg[3][t] = y1; sg[4][t] = ar;
  }
  __syncthreads();

  u32 m = 0;   // bit k: anchor base+64k+lane has iou>=0.7 vs any of this thread's gts
  for (int gp = wave; gp < 8; gp += 4) {
    const int gi = gp * 4;
    const float g0x0 = sg[0][gi],   g0y0 = sg[1][gi],   g0x1 = sg[2][gi],   g0y1 = sg[3][gi],   g0a = sg[4][gi];
    const float g1x0 = sg[0][gi+1], g1y0 = sg[1][gi+1], g1x1 = sg[2][gi+1], g1y1 = sg[3][gi+1], g1a = sg[4][gi+1];
    const float g2x0 = sg[0][gi+2], g2y0 = sg[1][gi+2], g2x1 = sg[2][gi+2], g2y1 = sg[3][gi+2], g2a = sg[4][gi+2];
    const float g3x0 = sg[0][gi+3], g3y0 = sg[1][gi+3], g3x1 = sg[2][gi+3], g3y1 = sg[3][gi+3], g3a = sg[4][gi+3];
    u64 t0[4] = {0,0,0,0}, t1[4] = {0,0,0,0}, t2[4] = {0,0,0,0}, t3[4] = {0,0,0,0};
    u32 h0 = 0, h1 = 0, h2 = 0, h3 = 0;
    u32 bit = 1u;
    for (int j = lane; j < cnt; j += 64, bit <<= 1) {
      float4 x = sxy[j];
      float aarea = (x.z - x.x) * (x.w - x.y);
      float v0 = iou_pair(x.x, x.y, x.z, x.w, aarea, g0x0, g0y0, g0x1, g0y1, g0a);
      float v1 = iou_pair(x.x, x.y, x.z, x.w, aarea, g1x0, g1y0, g1x1, g1y1, g1a);
      float v2 = iou_pair(x.x, x.y, x.z, x.w, aarea, g2x0, g2y0, g2x1, g2y1, g2a);
      float v3 = iou_pair(x.x, x.y, x.z, x.w, aarea, g3x0, g3y0, g3x1, g3y1, g3a);
      if (fmaxf(fmaxf(v0, v1), fmaxf(v2, v3)) >= 0.7f) m |= bit;
      u32 ni = ~(u32)(base + j);
      u32 vb0 = __float_as_uint(v0), vb1 = __float_as_uint(v1);
      u32 vb2 = __float_as_uint(v2), vb3 = __float_as_uint(v3);
      if (vb0 >= h0) { top4_insert(t0, ((u64)vb0 << 32) | (u64)ni); h0 = (u32)(t0[3] >> 32); }
      if (vb1 >= h1) { top4_insert(t1, ((u64)vb1 << 32) | (u64)ni); h1 = (u32)(t1[3] >> 32); }
      if (vb2 >= h2) { top4_insert(t2, ((u64)vb2 << 32) | (u64)ni); h2 = (u32)(t2[3] >> 32); }
      if (vb3 >= h3) { top4_insert(t3, ((u64)vb3 << 32) | (u64)ni); h3 = (u32)(t3[3] >> 32); }
    }
    wave_merge_top4(t0);
    wave_merge_top4(t1);
    wave_merge_top4(t2);
    wave_merge_top4(t3);
    if (lane == 0) {
      const int g = half * 32 + gi;
      u64* dst = partial + (((size_t)b * NS + s) * G_N + g) * 4;
      #pragma unroll
      for (int k = 0; k < 4; k++) {
        dst[k] = t0[k]; dst[4 + k] = t1[k]; dst[8 + k] = t2[k]; dst[12 + k] = t3[k];
      }
    }
  }

  wm[t] = m;
  __syncthreads();
  if (wave == 0) {
    u32 mc = wm[lane] | wm[64 + lane] | wm[128 + lane] | wm[192 + lane];
    u64* posH = (half ? posB : posA) + (size_t)b * NWORD + s * 32;
    for (int k = 0; k < 32; k++) {
      u64 bal = __ballot((mc >> k) & 1u);
      if (lane == 0) posH[k] = bal;    // plain store — every word covered exactly once
    }
  }
}

// ---------------- Kernel 2: merge partials -> top4; lq anchors -> posA ----------------
__launch_bounds__(64)
__global__ void k_top4_merge(const u64* __restrict__ partial, u64* __restrict__ top4,
                             u64* __restrict__ posA) {
  const int b = blockIdx.y, g = blockIdx.x, lane = threadIdx.x;
  u64 top[4] = {0ull, 0ull, 0ull, 0ull};
  const u64* pb = partial + ((size_t)b * NS * G_N + g) * 4;
  for (int i = lane; i < NS * 4; i += 64) {
    u64 key = pb[(size_t)(i >> 2) * (G_N * 4) + (i & 3)];
    top4_insert(top, key);
  }
  wave_merge_top4(top);
  if (lane == 0) {
    u64* dst = top4 + ((size_t)b * G_N + g) * 4;
    #pragma unroll
    for (int k = 0; k < 4; k++) dst[k] = top[k];
  }
  // low-quality matches: every partial entry whose value bits == hq bits.
  u32 hqb = (u32)(__shfl(top[0], 0) >> 32);
  for (int i = lane; i < NS * 4; i += 64) {
    u64 key = pb[(size_t)(i >> 2) * (G_N * 4) + (i & 3)];
    u32 aidx = ~(u32)key;
    if ((u32)(key >> 32) == hqb && aidx < A_N)
      atomicOr(&posA[(size_t)b * NWORD + (aidx >> 6)], 1ull << (aidx & 63));
  }
}

// ---------------- Kernel 3: per-image npos + LDS histogram ----------------
__launch_bounds__(256)
__global__ void k_hist(const u64* __restrict__ posA, const u64* __restrict__ posB,
                       u32* __restrict__ npos, u32* __restrict__ hist) {
  const int b = blockIdx.x;
  const int t = threadIdx.x;
  __shared__ u32 sh[4096];
  __shared__ u32 stot;
  for (int i = t; i < 4096; i += 256) sh[i] = 0;
  if (t == 0) stot = 0;
  u32 k0, k1; image_key(b, k0, k1);
  __syncthreads();

  const u64* pa = posA + (size_t)b * NWORD;
  const u64* pb = posB + (size_t)b * NWORD;
  u32 c = 0;
  for (int i = t; i < NWORD; i += 256) {
    u64 w = pa[i] | pb[i];
    c += (u32)__popcll(w);
    while (w) {
      int bit = __ffsll((long long)w) - 1; w &= w - 1;
      u32 a = (u32)(i * 64 + bit);
      atomicAdd(&sh[rbits_for(k0, k1, a) >> 20], 1u);
    }
  }
  #pragma unroll
  for (int off = 32; off >= 1; off >>= 1) c += __shfl_xor(c, off);
  if ((t & 63) == 0 && c) atomicAdd(&stot, c);
  __syncthreads();
  for (int i = t; i < 4096; i += 256) hist[b * 4096 + i] = sh[i];
  if (t == 0) npos[b] = stot;
}

// ---------------- Kernel 4: per-image target bin ----------------
__launch_bounds__(256)
__global__ void k_bin(const u32* __restrict__ npos, const u32* __restrict__ hist,
                      int2* __restrict__ binsel) {
  const int b = blockIdx.x;
  const int t = threadIdx.x;
  __shared__ u32 part[256];
  const u32* hb = hist + b * 4096;
  u32 local = 0;
  for (int j = 0; j < 16; j++) local += hb[t * 16 + j];
  part[t] = local;
  __syncthreads();
  if (t == 0) {
    if (npos[b] <= MAX_POS) {
      binsel[b] = make_int2(-1, 0);
    } else {
      u32 cum = 0; int chunk = 0;
      for (int i = 0; i < 256; i++) {
        if (cum + part[i] >= MAX_POS) { chunk = i; break; }
        cum += part[i];
      }
      int tb = chunk * 16; u32 before = cum;
      for (int j = 0; j < 16; j++) {
        u32 h = hb[chunk * 16 + j];
        if (before + h >= MAX_POS) { tb = chunk * 16 + j; break; }
        before += h;
      }
      binsel[b] = make_int2(tb, (int)before);
    }
  }
}

// ---------------- Kernel 5: collect fine candidates in target bin ----------------
__launch_bounds__(256)
__global__ void k_collect(const u64* __restrict__ posA, const u64* __restrict__ posB,
                          const int2* __restrict__ binsel,
                          u32* __restrict__ fine, u32* __restrict__ fcnt) {
  const int b = blockIdx.y;
  const int stb = binsel[b].x;
  if (stb < 0) return;
  u32 k0, k1; image_key(b, k0, k1);
  const int a0 = blockIdx.x * AS;
  const u64* pa = posA + (size_t)b * NWORD;
  const u64* pb = posB + (size_t)b * NWORD;
  for (int j = threadIdx.x; j < AS; j += 256) {
    int a = a0 + j;
    if (a >= A_N) break;
    if (!(((pa[a >> 6] | pb[a >> 6]) >> (a & 63)) & 1ull)) continue;
    u32 rb = rbits_for(k0, k1, (u32)a);
    if ((int)(rb >> 20) != stb) continue;
    u32 idx = atomicAdd(&fcnt[b], 1u);
    if (idx < FINE_CAP) fine[b * FINE_CAP + idx] = (((rb >> 9) & 0x7FFu) << 18) | (u32)a;
  }
}

// ---------------- Kernel 6: exact 128th-smallest threshold (1 wave/image) ----------------
__launch_bounds__(64)
__global__ void k_tstar(const int2* __restrict__ binsel, const u32* __restrict__ fine,
                        const u32* __restrict__ fcnt, u64* __restrict__ Tstar) {
  const int b = blockIdx.x;
  const int lane = threadIdx.x;
  int2 bs = binsel[b];
  if (bs.x < 0) { if (lane == 0) Tstar[b] = ~0ull; return; }
  const int m = min((int)fcnt[b], FINE_CAP);
  const u32 need = (u32)(MAX_POS - bs.y);   // >= 1
  const u32* fb = fine + b * FINE_CAP;
  u32 lo = 0, hi = (1u << 29) - 1;
  while (lo < hi) {
    u32 mid = lo + ((hi - lo) >> 1);
    u32 c = 0;
    for (int j = lane; j < m; j += 64) c += (fb[j] <= mid) ? 1u : 0u;
    #pragma unroll
    for (int off = 32; off >= 1; off >>= 1) c += __shfl_xor(c, off);
    if (c >= need) hi = mid; else lo = mid + 1;   // uniform across wave
  }
  if (lane == 0) Tstar[b] = ((u64)(u32)bs.x << 29) | (u64)lo;   // 41-bit threshold
}

// ---------------- Kernel 7: per-gt counts (argmax only for selected) ----------------
__launch_bounds__(256)
__global__ void k_count(const float4* __restrict__ anchors, const float4* __restrict__ gt,
                        const u64* __restrict__ posA, const u64* __restrict__ posB,
                        const u64* __restrict__ Tstar, u32* __restrict__ cnt) {
  const int b = blockIdx.y;
  const int t = threadIdx.x;
  __shared__ float sg[5][64];
  if (t < 64) {
    float x0, y0, x1, y1, ar;
    conv_box(gt[(size_t)b * G_N + t], x0, y0, x1, y1, ar);
    sg[0][t] = x0; sg[1][t] = y0; sg[2][t] = x1; sg[3][t] = y1; sg[4][t] = ar;
  }
  __syncthreads();
  u32 k0, k1; image_key(b, k0, k1);
  const u64 T = Tstar[b];
  const int a0 = blockIdx.x * AS;
  const u64* pa = posA + (size_t)b * NWORD;
  const u64* pb = posB + (size_t)b * NWORD;
  const float4* ab = anchors + (size_t)b * A_N;
  for (int j = t; j < AS; j += 256) {
    int a = a0 + j;
    if (a >= A_N) break;
    if (!(((pa[a >> 6] | pb[a >> 6]) >> (a & 63)) & 1ull)) continue;
    if (T != ~0ull) {
      u32 rb = rbits_for(k0, k1, (u32)a);
      if (((((u64)(rb >> 9)) << 18) | (u64)(u32)a) > T) continue;
    }
    float ax0, ay0, ax1, ay1, aar;
    conv_box(ab[a], ax0, ay0, ax1, ay1, aar);
    float bv = -1.0f; int g0 = 0;
    for (int g = 0; g < 64; g++) {
      float v = iou_pair(ax0, ay0, ax1, ay1, aar,
                         sg[0][g], sg[1][g], sg[2][g], sg[3][g], sg[4][g]);
      if (v > bv) { bv = v; g0 = g; }   // strict > = first max (jnp.argmax)
    }
    atomicAdd(&cnt[b * G_N + g0], 1u);
  }
}

// ---------------- Kernel 8: output ----------------
__launch_bounds__(64)
__global__ void k_out(const u64* __restrict__ top4, const u32* __restrict__ cnt,
                      float* __restrict__ out, int sec) {
  const int b = blockIdx.x;
  const int g = threadIdx.x;   // 64 threads
  const u32 c = min(cnt[b * G_N + g], (u32)K_TOP);
  const u64* t4 = top4 + ((size_t)b * G_N + g) * 4;
  #pragma unroll
  for (int k = 0; k < 4; k++) {
    u64 key = t4[k];
    u32 fb = (u32)(key >> 32);
    u32 aidx = ~(u32)key;
    bool valid = (u32)k < c;
    int o = b * (G_N * K_TOP) + g * K_TOP + k;
    out[0 * sec + o] = valid ? (float)aidx : -1.0f;          // pr_inds
    out[1 * sec + o] = valid ? (float)g : -1.0f;             // gt_inds
    out[2 * sec + o] = valid ? 1.0f : 0.0f;                  // valid mask
    out[3 * sec + o] = valid ? __uint_as_float(fb) : 0.0f;   // topk ious
  }
}

extern "C" void kernel_launch(void* const* d_in, const int* in_sizes, int n_in,
                              void* d_out, int out_size, void* d_ws, size_t ws_size,
                              hipStream_t stream) {
  const float4* anchors = (const float4*)d_in[0];  // [B, A, 4] cxcywh
  const float4* gt      = (const float4*)d_in[1];  // [B, G, 4] cxcywh
  float* out = (float*)d_out;                      // 4 x [B, G*K] concatenated

  // Layout (total 2,025,536 B):
  //   top4    @ 0          (16,384)
  //   partial @ 16,384     (1,605,632) — dead after k_top4_merge; aliased by:
  //       fine   @ 16,384    (131,072)
  //       hist   @ 147,456   (131,072)  [written whole by k_hist — no init]
  //       binsel @ 278,528   (64)
  //       Tstar  @ 278,592   (64)
  //   posA    @ 1,622,016  (200,704)  [fully ballot-stored — no init]
  //   posB    @ 1,822,720  (200,704)  [fully ballot-stored — no init]
  //   zr      @ 2,023,424  (2,112): npos(32) fcnt(32) cnt(2,048)
  char* ws = (char*)d_ws;
  u64*  top4    = (u64*)(ws);
  u64*  partial = (u64*)(ws + 16384);
  u32*  fine    = (u32*)(ws + 16384);
  u32*  hist    = (u32*)(ws + 147456);
  int2* binsel  = (int2*)(ws + 278528);
  u64*  Tstar   = (u64*)(ws + 278592);
  u64*  posA    = (u64*)(ws + 1622016);
  u64*  posB    = (u64*)(ws + 1822720);
  char* zr      = ws + 2023424;
  u32*  npos    = (u32*)(zr);
  u32*  fcnt    = (u32*)(zr + 32);
  u32*  cnt     = (u32*)(zr + 64);

  hipMemsetAsync(zr, 0, 2112, stream);

  int sec = out_size / 4;  // 2048 = B*G*K

  k_top4_part <<<dim3(NS, B_IMG * 2), 256, 0, stream>>>(anchors, gt, partial, posA, posB);
  k_top4_merge<<<dim3(G_N, B_IMG), 64, 0, stream>>>(partial, top4, posA);
  k_hist      <<<dim3(B_IMG), 256, 0, stream>>>(posA, posB, npos, hist);
  k_bin       <<<dim3(B_IMG), 256, 0, stream>>>(npos, hist, binsel);
  k_collect   <<<dim3(NS, B_IMG), 256, 0, stream>>>(posA, posB, binsel, fine, fcnt);
  k_tstar     <<<dim3(B_IMG), 64, 0, stream>>>(binsel, fine, fcnt, Tstar);
  k_count     <<<dim3(NS, B_IMG), 256, 0, stream>>>(anchors, gt, posA, posB, Tstar, cnt);
  k_out       <<<dim3(B_IMG), 64, 0, stream>>>(top4, cnt, out, sec);
}

// Round 8
// 360.400 us; speedup vs baseline: 2.1340x; 1.0112x over previous
//
#include <hip/hip_runtime.h>
#include <stdint.h>

// Stage1Assigner (RPN matcher + subsample + top-k per GT) for MI355X.
// B=8 images, A=200000 anchors, G=64 GTs, K=4, thresholds 0.3/0.7, 128 max pos.
//
// PRNG: JAX threefry, jax_threefry_partitionable=True:
//   keys[b] = threefry2x32((0,42),(0,b));  bits[a] = y0^y1 of threefry2x32(key_b,(0,a))
// Selection of 128 positives = 128 lexicographically smallest (bits>>9, a).
//
// 6 dispatches, no memset. WORKSPACE LAYOUT IS CAPPED AT THE R5-PROVEN
// 2,025,536 B — R6 grew it past 2 MiB and corrupted adjacent allocations
// (passed fresh launch, diverged during graph replays).
//   k_top4_part  hot kernel (R5-proven inner loop, AS=2048, 4 blocks/CU):
//                per-(slice,gt) top-4 + >=0.7 ballots -> posA/posB plain stores;
//                s==0,half==0 blocks zero fcnt/cnt (fresh region, later-read only).
//   k_top4_merge single-pass register merge -> top4/hq; lq anchors atomicOr posA.
//   k_hist       1 block/image: LDS hist (4096 bins of rbits>>20) + npos,
//                plain-stored wholesale -> hist may alias dead partial.
//   k_collect    grid (NS,8): per-block local bin selection from hist (redundant,
//                parallel), writes binsel (duplicate identical), fine keys.
//   k_count      grid (NS,8): wave-0 local Tstar (binary search over fine),
//                argmax-gt recomputed ONLY for <=128 selected anchors -> cnt.
//   k_out        emit (pr, gt, valid, scores).
//
// IoU is fp-contract(off) IEEE per-op: identical bits across all passes and
// matches XLA per-HLO rounding.

#pragma clang fp contract(off)

#define B_IMG 8
#define A_N 200000
#define G_N 64
#define K_TOP 4
#define MAX_POS 128
#define FINE_CAP 4096
#define AS 2048
#define NS 98            // ceil(200000/2048)
#define WPS 32           // u64 ballot words per slice
#define NWORD 3136       // NS*WPS words of pos bits per image

typedef unsigned long long u64;
typedef unsigned int u32;

__device__ __forceinline__ u32 rotl32(u32 v, int n) { return (v << n) | (v >> (32 - n)); }

__device__ __forceinline__ void tf_round(u32& x0, u32& x1, int r) {
  x0 += x1; x1 = rotl32(x1, r); x1 ^= x0;
}

__device__ __forceinline__ void threefry2x32(u32 k0, u32 k1, u32& x0, u32& x1) {
  u32 ks2 = 0x1BD11BDAu ^ k0 ^ k1;
  x0 += k0; x1 += k1;
  tf_round(x0,x1,13); tf_round(x0,x1,15); tf_round(x0,x1,26); tf_round(x0,x1,6);
  x0 += k1; x1 += ks2 + 1u;
  tf_round(x0,x1,17); tf_round(x0,x1,29); tf_round(x0,x1,16); tf_round(x0,x1,24);
  x0 += ks2; x1 += k0 + 2u;
  tf_round(x0,x1,13); tf_round(x0,x1,15); tf_round(x0,x1,26); tf_round(x0,x1,6);
  x0 += k0; x1 += k1 + 3u;
  tf_round(x0,x1,17); tf_round(x0,x1,29); tf_round(x0,x1,16); tf_round(x0,x1,24);
  x0 += k1; x1 += ks2 + 4u;
  tf_round(x0,x1,13); tf_round(x0,x1,15); tf_round(x0,x1,26); tf_round(x0,x1,6);
  x0 += ks2; x1 += k0 + 5u;
}

__device__ __forceinline__ void image_key(int b, u32& kb0, u32& kb1) {
  u32 x0 = 0u, x1 = (u32)b;
  threefry2x32(0u, 42u, x0, x1);
  kb0 = x0; kb1 = x1;
}

__device__ __forceinline__ u32 rbits_for(u32 k0, u32 k1, u32 a) {
  u32 x0 = 0u, x1 = a;
  threefry2x32(k0, k1, x0, x1);
  return x0 ^ x1;
}

__device__ __forceinline__ void conv_box(float4 bx, float& x0, float& y0,
                                         float& x1, float& y1, float& area) {
  #pragma clang fp contract(off)
  x0 = bx.x - 0.5f * bx.z;
  y0 = bx.y - 0.5f * bx.w;
  x1 = bx.x + 0.5f * bx.z;
  y1 = bx.y + 0.5f * bx.w;
  area = (x1 - x0) * (y1 - y0);
}

__device__ __forceinline__ float iou_pair(float ax0, float ay0, float ax1, float ay1, float aarea,
                                          float gx0, float gy0, float gx1, float gy1, float garea) {
  #pragma clang fp contract(off)
  float ltx = fmaxf(gx0, ax0), lty = fmaxf(gy0, ay0);
  float rbx = fminf(gx1, ax1), rby = fminf(gy1, ay1);
  float w = fmaxf(rbx - ltx, 0.0f), h = fmaxf(rby - lty, 0.0f);
  float inter = w * h;
  float uni = (garea + aarea) - inter;
  return inter / uni;
}

__device__ __forceinline__ void top4_insert(u64 (&top)[4], u64 key) {
  if (key > top[3]) {
    if (key > top[0])      { top[3]=top[2]; top[2]=top[1]; top[1]=top[0]; top[0]=key; }
    else if (key > top[1]) { top[3]=top[2]; top[2]=top[1]; top[1]=key; }
    else if (key > top[2]) { top[3]=top[2]; top[2]=key; }
    else                   { top[3]=key; }
  }
}

__device__ __forceinline__ void wave_merge_top4(u64 (&top)[4]) {
  for (int off = 32; off >= 1; off >>= 1) {
    u64 o[4];
    #pragma unroll
    for (int k = 0; k < 4; k++) o[k] = __shfl_down(top[k], (unsigned)off);
    u64 m[4]; int i = 0, j = 0;
    #pragma unroll
    for (int k = 0; k < 4; k++) m[k] = (top[i] >= o[j]) ? top[i++] : o[j++];
    #pragma unroll
    for (int k = 0; k < 4; k++) top[k] = m[k];
  }
}

// ---------------- Kernel 1: per-(slice, b, gt-half) top-4 + pos-bit ballot ----------------
// grid (NS, B*2); block 256 = 4 waves; wave w handles 4-gt groups {w, w+4} of its half.
__launch_bounds__(256, 4)
__global__ void k_top4_part(const float4* __restrict__ anchors, const float4* __restrict__ gt,
                            u64* __restrict__ partial,
                            u64* __restrict__ posA, u64* __restrict__ posB,
                            u32* __restrict__ fcnt, u32* __restrict__ cnt) {
  const int s = blockIdx.x;
  const int b = blockIdx.y >> 1, half = blockIdx.y & 1;
  const int t = threadIdx.x;
  const int wave = t >> 6, lane = t & 63;

  __shared__ float4 sxy[AS];        // converted xyxy (area recomputed inline)
  __shared__ float  sg[5][32];
  __shared__ u32    wm[256];

  if (s == 0 && half == 0) {        // zero small state (read only in later dispatches)
    if (t < 64) cnt[b * G_N + t] = 0;
    if (t == 0) fcnt[b] = 0;
  }

  const int base = s * AS;
  const int acnt = min(AS, A_N - base);
  const float4* ab = anchors + (size_t)b * A_N + base;

  for (int j = t; j < acnt; j += 256) {
    float x0, y0, x1, y1, ar;
    conv_box(ab[j], x0, y0, x1, y1, ar);
    sxy[j] = make_float4(x0, y0, x1, y1);
  }
  if (t < 32) {
    float x0, y0, x1, y1, ar;
    conv_box(gt[(size_t)b * G_N + half * 32 + t], x0, y0, x1, y1, ar);
    sg[0][t] = x0; sg[1][t] = y0; sg[2][t] = x1; sg[3][t] = y1; sg[4][t] = ar;
  }
  __syncthreads();

  u32 m = 0;   // bit k: anchor base+64k+lane has iou>=0.7 vs any of this thread's gts
  for (int gp = wave; gp < 8; gp += 4) {
    const int gi = gp * 4;
    const float g0x0 = sg[0][gi],   g0y0 = sg[1][gi],   g0x1 = sg[2][gi],   g0y1 = sg[3][gi],   g0a = sg[4][gi];
    const float g1x0 = sg[0][gi+1], g1y0 = sg[1][gi+1], g1x1 = sg[2][gi+1], g1y1 = sg[3][gi+1], g1a = sg[4][gi+1];
    const float g2x0 = sg[0][gi+2], g2y0 = sg[1][gi+2], g2x1 = sg[2][gi+2], g2y1 = sg[3][gi+2], g2a = sg[4][gi+2];
    const float g3x0 = sg[0][gi+3], g3y0 = sg[1][gi+3], g3x1 = sg[2][gi+3], g3y1 = sg[3][gi+3], g3a = sg[4][gi+3];
    u64 t0[4] = {0,0,0,0}, t1[4] = {0,0,0,0}, t2[4] = {0,0,0,0}, t3[4] = {0,0,0,0};
    u32 h0 = 0, h1 = 0, h2 = 0, h3 = 0;
    u32 bit = 1u;
    for (int j = lane; j < acnt; j += 64, bit <<= 1) {
      float4 x = sxy[j];
      float aarea = (x.z - x.x) * (x.w - x.y);
      float v0 = iou_pair(x.x, x.y, x.z, x.w, aarea, g0x0, g0y0, g0x1, g0y1, g0a);
      float v1 = iou_pair(x.x, x.y, x.z, x.w, aarea, g1x0, g1y0, g1x1, g1y1, g1a);
      float v2 = iou_pair(x.x, x.y, x.z, x.w, aarea, g2x0, g2y0, g2x1, g2y1, g2a);
      float v3 = iou_pair(x.x, x.y, x.z, x.w, aarea, g3x0, g3y0, g3x1, g3y1, g3a);
      if (fmaxf(fmaxf(v0, v1), fmaxf(v2, v3)) >= 0.7f) m |= bit;
      u32 ni = ~(u32)(base + j);
      u32 vb0 = __float_as_uint(v0), vb1 = __float_as_uint(v1);
      u32 vb2 = __float_as_uint(v2), vb3 = __float_as_uint(v3);
      if (vb0 >= h0) { top4_insert(t0, ((u64)vb0 << 32) | (u64)ni); h0 = (u32)(t0[3] >> 32); }
      if (vb1 >= h1) { top4_insert(t1, ((u64)vb1 << 32) | (u64)ni); h1 = (u32)(t1[3] >> 32); }
      if (vb2 >= h2) { top4_insert(t2, ((u64)vb2 << 32) | (u64)ni); h2 = (u32)(t2[3] >> 32); }
      if (vb3 >= h3) { top4_insert(t3, ((u64)vb3 << 32) | (u64)ni); h3 = (u32)(t3[3] >> 32); }
    }
    wave_merge_top4(t0);
    wave_merge_top4(t1);
    wave_merge_top4(t2);
    wave_merge_top4(t3);
    if (lane == 0) {
      const int g = half * 32 + gi;
      u64* dst = partial + (((size_t)b * NS + s) * G_N + g) * 4;
      #pragma unroll
      for (int k = 0; k < 4; k++) {
        dst[k] = t0[k]; dst[4 + k] = t1[k]; dst[8 + k] = t2[k]; dst[12 + k] = t3[k];
      }
    }
  }

  wm[t] = m;
  __syncthreads();
  if (wave == 0) {
    u32 mc = wm[lane] | wm[64 + lane] | wm[128 + lane] | wm[192 + lane];
    u64* posH = (half ? posB : posA) + (size_t)b * NWORD + s * WPS;
    for (int k = 0; k < WPS; k++) {
      u64 bal = __ballot((mc >> k) & 1u);
      if (lane == 0) posH[k] = bal;    // plain store — every word covered exactly once
    }
  }
}

// ---------------- Kernel 2: merge partials -> top4; lq anchors -> posA ----------------
__launch_bounds__(64)
__global__ void k_top4_merge(const u64* __restrict__ partial, u64* __restrict__ top4,
                             u64* __restrict__ posA) {
  const int b = blockIdx.y, g = blockIdx.x, lane = threadIdx.x;
  const u64* pb = partial + ((size_t)b * NS * G_N + g) * 4;
  u64 keys[7];                       // NS*4 = 392 -> <= 7 per lane
  int nk = 0;
  for (int i = lane; i < NS * 4; i += 64)
    keys[nk++] = pb[(size_t)(i >> 2) * (G_N * 4) + (i & 3)];
  u64 top[4] = {0ull, 0ull, 0ull, 0ull};
  for (int q = 0; q < nk; q++) top4_insert(top, keys[q]);
  wave_merge_top4(top);
  if (lane == 0) {
    u64* dst = top4 + ((size_t)b * G_N + g) * 4;
    #pragma unroll
    for (int k = 0; k < 4; k++) dst[k] = top[k];
  }
  // low-quality matches: every partial entry whose value bits == hq bits.
  u32 hqb = (u32)(__shfl(top[0], 0) >> 32);
  for (int q = 0; q < nk; q++) {
    u64 key = keys[q];
    u32 aidx = ~(u32)key;
    if ((u32)(key >> 32) == hqb && aidx < A_N)
      atomicOr(&posA[(size_t)b * NWORD + (aidx >> 6)], 1ull << (aidx & 63));
  }
}

// ---------------- Kernel 3: per-image npos + LDS histogram (plain-stored) ----------------
__launch_bounds__(256)
__global__ void k_hist(const u64* __restrict__ posA, const u64* __restrict__ posB,
                       u32* __restrict__ npos, u32* __restrict__ hist) {
  const int b = blockIdx.x;
  const int t = threadIdx.x;
  __shared__ u32 sh[4096];
  __shared__ u32 stot;
  for (int i = t; i < 4096; i += 256) sh[i] = 0;
  if (t == 0) stot = 0;
  u32 k0, k1; image_key(b, k0, k1);
  __syncthreads();

  const u64* pa = posA + (size_t)b * NWORD;
  const u64* pb = posB + (size_t)b * NWORD;
  u32 c = 0;
  for (int i = t; i < NWORD; i += 256) {
    u64 w = pa[i] | pb[i];
    c += (u32)__popcll(w);
    while (w) {
      int bit = __ffsll((long long)w) - 1; w &= w - 1;
      u32 a = (u32)(i * 64 + bit);
      atomicAdd(&sh[rbits_for(k0, k1, a) >> 20], 1u);
    }
  }
  #pragma unroll
  for (int off = 32; off >= 1; off >>= 1) c += __shfl_xor(c, off);
  if ((t & 63) == 0 && c) atomicAdd(&stot, c);
  __syncthreads();
  for (int i = t; i < 4096; i += 256) hist[b * 4096 + i] = sh[i];   // wholesale store
  if (t == 0) npos[b] = stot;
}

// ---------------- Kernel 4: local bin selection + collect fine candidates ----------------
// grid (NS, B).
__launch_bounds__(256)
__global__ void k_collect(const u64* __restrict__ posA, const u64* __restrict__ posB,
                          const u32* __restrict__ npos, const u32* __restrict__ hist,
                          int2* __restrict__ binsel,
                          u32* __restrict__ fine, u32* __restrict__ fcnt) {
  const int b = blockIdx.y;
  const int t = threadIdx.x;
  __shared__ u32 red[256];
  __shared__ int sbin;

  const u32* hb = hist + b * 4096;
  u32 local = 0;
  for (int j = 0; j < 16; j++) local += hb[t * 16 + j];
  red[t] = local;
  __syncthreads();
  if (t == 0) {
    if (npos[b] <= MAX_POS) {
      sbin = -1;
      binsel[b] = make_int2(-1, 0);          // duplicate identical writes across blocks
    } else {
      u32 cum = 0; int chunk = 0;
      for (int i = 0; i < 256; i++) {
        if (cum + red[i] >= MAX_POS) { chunk = i; break; }
        cum += red[i];
      }
      int tb = chunk * 16; u32 before = cum;
      for (int j = 0; j < 16; j++) {
        u32 h = hb[chunk * 16 + j];
        if (before + h >= MAX_POS) { tb = chunk * 16 + j; break; }
        before += h;
      }
      sbin = tb;
      binsel[b] = make_int2(tb, (int)before);
    }
  }
  __syncthreads();
  const int stb = sbin;
  if (stb < 0) return;

  u32 k0, k1; image_key(b, k0, k1);
  const int a0 = blockIdx.x * AS;
  const u64* pa = posA + (size_t)b * NWORD;
  const u64* pb = posB + (size_t)b * NWORD;
  for (int j = t; j < AS; j += 256) {
    int a = a0 + j;
    if (a >= A_N) break;
    if (!(((pa[a >> 6] | pb[a >> 6]) >> (a & 63)) & 1ull)) continue;
    u32 rb = rbits_for(k0, k1, (u32)a);
    if ((int)(rb >> 20) != stb) continue;
    u32 idx = atomicAdd(&fcnt[b], 1u);
    if (idx < FINE_CAP) fine[b * FINE_CAP + idx] = (((rb >> 9) & 0x7FFu) << 18) | (u32)a;
  }
}

// ---------------- Kernel 5: local Tstar + per-gt counts of selected ----------------
// grid (NS, B).
__launch_bounds__(256)
__global__ void k_count(const float4* __restrict__ anchors, const float4* __restrict__ gt,
                        const u64* __restrict__ posA, const u64* __restrict__ posB,
                        const int2* __restrict__ binsel, const u32* __restrict__ fine,
                        const u32* __restrict__ fcnt, u32* __restrict__ cnt) {
  const int b = blockIdx.y;
  const int t = threadIdx.x;
  __shared__ float sg[5][64];
  __shared__ u64 sT;

  if (t < 64) {
    float x0, y0, x1, y1, ar;
    conv_box(gt[(size_t)b * G_N + t], x0, y0, x1, y1, ar);
    sg[0][t] = x0; sg[1][t] = y0; sg[2][t] = x1; sg[3][t] = y1; sg[4][t] = ar;
    // wave 0: compute Tstar locally (binary search over the small fine list)
    int2 bs = binsel[b];
    u64 T = ~0ull;
    if (bs.x >= 0) {
      const int m = min((int)fcnt[b], FINE_CAP);
      const u32 need = (u32)(MAX_POS - bs.y);   // >= 1
      const u32* fb = fine + b * FINE_CAP;
      u32 lo = 0, hi = (1u << 29) - 1;
      while (lo < hi) {
        u32 mid = lo + ((hi - lo) >> 1);
        u32 c = 0;
        for (int j = t; j < m; j += 64) c += (fb[j] <= mid) ? 1u : 0u;
        #pragma unroll
        for (int off = 32; off >= 1; off >>= 1) c += __shfl_xor(c, off);
        if (c >= need) hi = mid; else lo = mid + 1;   // uniform across wave
      }
      T = ((u64)(u32)bs.x << 29) | (u64)lo;   // 41-bit threshold
    }
    if (t == 0) sT = T;
  }
  __syncthreads();

  u32 k0, k1; image_key(b, k0, k1);
  const u64 T = sT;
  const int a0 = blockIdx.x * AS;
  const u64* pa = posA + (size_t)b * NWORD;
  const u64* pb = posB + (size_t)b * NWORD;
  const float4* ab = anchors + (size_t)b * A_N;
  for (int j = t; j < AS; j += 256) {
    int a = a0 + j;
    if (a >= A_N) break;
    if (!(((pa[a >> 6] | pb[a >> 6]) >> (a & 63)) & 1ull)) continue;
    if (T != ~0ull) {
      u32 rb = rbits_for(k0, k1, (u32)a);
      if (((((u64)(rb >> 9)) << 18) | (u64)(u32)a) > T) continue;
    }
    float ax0, ay0, ax1, ay1, aar;
    conv_box(ab[a], ax0, ay0, ax1, ay1, aar);
    float bv = -1.0f; int g0 = 0;
    for (int g = 0; g < 64; g++) {
      float v = iou_pair(ax0, ay0, ax1, ay1, aar,
                         sg[0][g], sg[1][g], sg[2][g], sg[3][g], sg[4][g]);
      if (v > bv) { bv = v; g0 = g; }   // strict > = first max (jnp.argmax)
    }
    atomicAdd(&cnt[b * G_N + g0], 1u);
  }
}

// ---------------- Kernel 6: output ----------------
__launch_bounds__(64)
__global__ void k_out(const u64* __restrict__ top4, const u32* __restrict__ cnt,
                      float* __restrict__ out, int sec) {
  const int b = blockIdx.x;
  const int g = threadIdx.x;   // 64 threads
  const u32 c = min(cnt[b * G_N + g], (u32)K_TOP);
  const u64* t4 = top4 + ((size_t)b * G_N + g) * 4;
  #pragma unroll
  for (int k = 0; k < 4; k++) {
    u64 key = t4[k];
    u32 fb = (u32)(key >> 32);
    u32 aidx = ~(u32)key;
    bool valid = (u32)k < c;
    int o = b * (G_N * K_TOP) + g * K_TOP + k;
    out[0 * sec + o] = valid ? (float)aidx : -1.0f;          // pr_inds
    out[1 * sec + o] = valid ? (float)g : -1.0f;             // gt_inds
    out[2 * sec + o] = valid ? 1.0f : 0.0f;                  // valid mask
    out[3 * sec + o] = valid ? __uint_as_float(fb) : 0.0f;   // topk ious
  }
}

extern "C" void kernel_launch(void* const* d_in, const int* in_sizes, int n_in,
                              void* d_out, int out_size, void* d_ws, size_t ws_size,
                              hipStream_t stream) {
  const float4* anchors = (const float4*)d_in[0];  // [B, A, 4] cxcywh
  const float4* gt      = (const float4*)d_in[1];  // [B, G, 4] cxcywh
  float* out = (float*)d_out;                      // 4 x [B, G*K] concatenated

  // Layout — IDENTICAL EXTENT to the R5-proven 2,025,536 B:
  //   top4    @ 0          (16,384)
  //   partial @ 16,384     (8*98*64*32 = 1,605,632) — dead after k_top4_merge;
  //     aliases (written only in dispatches >= 3):
  //       fine   @ 16,384    (131,072)  [k_collect]
  //       hist   @ 147,456   (131,072)  [k_hist, wholesale store — no init]
  //       binsel @ 278,528   (64)       [k_collect]
  //   posA    @ 1,622,016  (200,704)  [fully ballot-stored — no init]
  //   posB    @ 1,822,720  (200,704)  [fully ballot-stored — no init]
  //   small   @ 2,023,424  (2,112): npos(32) [plain-stored by k_hist],
  //            fcnt(32) + cnt(2,048) [zeroed by k_top4_part s==0 blocks]
  char* ws = (char*)d_ws;
  u64*  top4    = (u64*)(ws);
  u64*  partial = (u64*)(ws + 16384);
  u32*  fine    = (u32*)(ws + 16384);
  u32*  hist    = (u32*)(ws + 147456);
  int2* binsel  = (int2*)(ws + 278528);
  u64*  posA    = (u64*)(ws + 1622016);
  u64*  posB    = (u64*)(ws + 1822720);
  u32*  npos    = (u32*)(ws + 2023424);
  u32*  fcnt    = (u32*)(ws + 2023456);
  u32*  cnt     = (u32*)(ws + 2023488);

  int sec = out_size / 4;  // 2048 = B*G*K

  k_top4_part <<<dim3(NS, B_IMG * 2), 256, 0, stream>>>(anchors, gt, partial, posA, posB,
                                                        fcnt, cnt);
  k_top4_merge<<<dim3(G_N, B_IMG), 64, 0, stream>>>(partial, top4, posA);
  k_hist      <<<dim3(B_IMG), 256, 0, stream>>>(posA, posB, npos, hist);
  k_collect   <<<dim3(NS, B_IMG), 256, 0, stream>>>(posA, posB, npos, hist, binsel, fine, fcnt);
  k_count     <<<dim3(NS, B_IMG), 256, 0, stream>>>(anchors, gt, posA, posB, binsel, fine, fcnt, cnt);
  k_out       <<<dim3(B_IMG), 64, 0, stream>>>(top4, cnt, out, sec);
}

// Round 9
// 334.318 us; speedup vs baseline: 2.3004x; 1.0780x over previous
//
#include <hip/hip_runtime.h>
#include <stdint.h>

// Stage1Assigner (RPN matcher + subsample + top-k per GT) for MI355X.
// B=8 images, A=200000 anchors, G=64 GTs, K=4, thresholds 0.3/0.7, 128 max pos.
//
// PRNG: JAX threefry, jax_threefry_partitionable=True:
//   keys[b] = threefry2x32((0,42),(0,b));  bits[a] = y0^y1 of threefry2x32(key_b,(0,a))
// Selection of 128 positives = 128 lexicographically smallest (bits>>9, a).
//
// Hot kernel (k_top4_part) is TWO-PASS per slice to kill the per-iteration
// IEEE-div + if-converted u64-insert cost (R7 measured ~580 instrs/iter):
//   pass 1: per-gt top-4 of approx q = inter*rcp(uni) (u32 sorted quad,
//           8 min/max, no index, no div, no branch); wave-merge -> Q4.
//   pass 2: conservative screen  inter >= t~ * uni  with
//           t~ = bits(min(Q4 - 16ulp, 0.7f - 8ulp)) - 8ulp  (safe: rcp err
//           <= ~2.5 ulp << 16-ulp slack; 8-ulp product margin covers binade
//           edges; denormal flush -> never-skip). Survivors only: exact f32
//           div, exact >=0.7 bit, ballot-guarded u64 top-4 insert.
//   All EXACT comparisons identical to R5/R7 -> bit-identical output.
// Value-0 fake entries (masked lanes insert vb=0 early) are displaced whenever
// a gt has >=4 anchors with iou>0 globally (guaranteed for uniform boxes).
//
// Tail: k_top4_merge -> k_zero (hist) -> k_hist (13,8 word-parallel, global
// atomics: cold kernel) -> k_collect -> k_count -> k_out.
// WORKSPACE layout capped at the R5/R7-proven 2,025,536 B (R6 overran it).
//
// IoU is fp-contract(off) IEEE per-op: identical bits across all passes and
// matches XLA per-HLO rounding.

#pragma clang fp contract(off)

#define B_IMG 8
#define A_N 200000
#define G_N 64
#define K_TOP 4
#define MAX_POS 128
#define FINE_CAP 4096
#define AS 2048
#define NS 98            // ceil(200000/2048)
#define WPS 32           // u64 ballot words per slice
#define NWORD 3136       // NS*WPS words of pos bits per image

typedef unsigned long long u64;
typedef unsigned int u32;

__device__ __forceinline__ u32 rotl32(u32 v, int n) { return (v << n) | (v >> (32 - n)); }

__device__ __forceinline__ void tf_round(u32& x0, u32& x1, int r) {
  x0 += x1; x1 = rotl32(x1, r); x1 ^= x0;
}

__device__ __forceinline__ void threefry2x32(u32 k0, u32 k1, u32& x0, u32& x1) {
  u32 ks2 = 0x1BD11BDAu ^ k0 ^ k1;
  x0 += k0; x1 += k1;
  tf_round(x0,x1,13); tf_round(x0,x1,15); tf_round(x0,x1,26); tf_round(x0,x1,6);
  x0 += k1; x1 += ks2 + 1u;
  tf_round(x0,x1,17); tf_round(x0,x1,29); tf_round(x0,x1,16); tf_round(x0,x1,24);
  x0 += ks2; x1 += k0 + 2u;
  tf_round(x0,x1,13); tf_round(x0,x1,15); tf_round(x0,x1,26); tf_round(x0,x1,6);
  x0 += k0; x1 += k1 + 3u;
  tf_round(x0,x1,17); tf_round(x0,x1,29); tf_round(x0,x1,16); tf_round(x0,x1,24);
  x0 += k1; x1 += ks2 + 4u;
  tf_round(x0,x1,13); tf_round(x0,x1,15); tf_round(x0,x1,26); tf_round(x0,x1,6);
  x0 += ks2; x1 += k0 + 5u;
}

__device__ __forceinline__ void image_key(int b, u32& kb0, u32& kb1) {
  u32 x0 = 0u, x1 = (u32)b;
  threefry2x32(0u, 42u, x0, x1);
  kb0 = x0; kb1 = x1;
}

__device__ __forceinline__ u32 rbits_for(u32 k0, u32 k1, u32 a) {
  u32 x0 = 0u, x1 = a;
  threefry2x32(k0, k1, x0, x1);
  return x0 ^ x1;
}

__device__ __forceinline__ void conv_box(float4 bx, float& x0, float& y0,
                                         float& x1, float& y1, float& area) {
  #pragma clang fp contract(off)
  x0 = bx.x - 0.5f * bx.z;
  y0 = bx.y - 0.5f * bx.w;
  x1 = bx.x + 0.5f * bx.z;
  y1 = bx.y + 0.5f * bx.w;
  area = (x1 - x0) * (y1 - y0);
}

__device__ __forceinline__ float iou_pair(float ax0, float ay0, float ax1, float ay1, float aarea,
                                          float gx0, float gy0, float gx1, float gy1, float garea) {
  #pragma clang fp contract(off)
  float ltx = fmaxf(gx0, ax0), lty = fmaxf(gy0, ay0);
  float rbx = fminf(gx1, ax1), rby = fminf(gy1, ay1);
  float w = fmaxf(rbx - ltx, 0.0f), h = fmaxf(rby - lty, 0.0f);
  float inter = w * h;
  float uni = (garea + aarea) - inter;
  return inter / uni;
}

// inter/uni only (no division) — same rounding sequence as iou_pair's prefix.
__device__ __forceinline__ void iou_parts(float ax0, float ay0, float ax1, float ay1, float aarea,
                                          float gx0, float gy0, float gx1, float gy1, float garea,
                                          float& inter, float& uni) {
  #pragma clang fp contract(off)
  float ltx = fmaxf(gx0, ax0), lty = fmaxf(gy0, ay0);
  float rbx = fminf(gx1, ax1), rby = fminf(gy1, ay1);
  float w = fmaxf(rbx - ltx, 0.0f), h = fmaxf(rby - lty, 0.0f);
  inter = w * h;
  uni = (garea + aarea) - inter;
}

__device__ __forceinline__ void top4_insert(u64 (&top)[4], u64 key) {
  if (key > top[3]) {
    if (key > top[0])      { top[3]=top[2]; top[2]=top[1]; top[1]=top[0]; top[0]=key; }
    else if (key > top[1]) { top[3]=top[2]; top[2]=top[1]; top[1]=key; }
    else if (key > top[2]) { top[3]=top[2]; top[2]=key; }
    else                   { top[3]=key; }
  }
}

__device__ __forceinline__ void wave_merge_top4(u64 (&top)[4]) {
  for (int off = 32; off >= 1; off >>= 1) {
    u64 o[4];
    #pragma unroll
    for (int k = 0; k < 4; k++) o[k] = __shfl_down(top[k], (unsigned)off);
    u64 m[4]; int i = 0, j = 0;
    #pragma unroll
    for (int k = 0; k < 4; k++) m[k] = (top[i] >= o[j]) ? top[i++] : o[j++];
    #pragma unroll
    for (int k = 0; k < 4; k++) top[k] = m[k];
  }
}

// branch-free sorted-desc 4-value insert (values only, u32 float bits)
__device__ __forceinline__ void ins4_val(u32 (&h)[4], u32 v) {
  u32 t = v, mx, mn;
  mx = max(t, h[0]); mn = min(t, h[0]); h[0] = mx; t = mn;
  mx = max(t, h[1]); mn = min(t, h[1]); h[1] = mx; t = mn;
  mx = max(t, h[2]); mn = min(t, h[2]); h[2] = mx; t = mn;
  h[3] = max(t, h[3]);
}

__device__ __forceinline__ void wave_merge_top4_u32(u32 (&top)[4]) {
  for (int off = 32; off >= 1; off >>= 1) {
    u32 o[4];
    #pragma unroll
    for (int k = 0; k < 4; k++) o[k] = __shfl_down(top[k], (unsigned)off);
    u32 m[4]; int i = 0, j = 0;
    #pragma unroll
    for (int k = 0; k < 4; k++) m[k] = (top[i] >= o[j]) ? top[i++] : o[j++];
    #pragma unroll
    for (int k = 0; k < 4; k++) top[k] = m[k];
  }
}

// conservative screen threshold: t~ = bitcast(max(tau,8)-8)  (tau = f32 bits)
__device__ __forceinline__ float screen_thresh(u32 tau) {
  u32 tb = (tau > 8u) ? (tau - 8u) : 0u;
  return __uint_as_float(tb);
}

// ---------------- Kernel 1: per-(slice, b, gt-half) top-4 + pos-bit ballot ----------------
// grid (NS, B*2); block 256 = 4 waves; wave w handles 4-gt groups {w, w+4} of its half.
__launch_bounds__(256, 4)
__global__ void k_top4_part(const float4* __restrict__ anchors, const float4* __restrict__ gt,
                            u64* __restrict__ partial,
                            u64* __restrict__ posA, u64* __restrict__ posB,
                            u32* __restrict__ npos, u32* __restrict__ fcnt,
                            u32* __restrict__ cnt) {
  const int s = blockIdx.x;
  const int b = blockIdx.y >> 1, half = blockIdx.y & 1;
  const int t = threadIdx.x;
  const int wave = t >> 6, lane = t & 63;

  __shared__ float4 sxy[AS];        // converted xyxy (area recomputed inline)
  __shared__ float  sg[5][32];
  __shared__ u32    wm[256];

  if (s == 0 && half == 0) {        // zero small state (read only in later dispatches)
    if (t < 64) cnt[b * G_N + t] = 0;
    if (t == 0) { fcnt[b] = 0; npos[b] = 0; }
  }

  const int base = s * AS;
  const int acnt = min(AS, A_N - base);
  const float4* ab = anchors + (size_t)b * A_N + base;

  for (int j = t; j < acnt; j += 256) {
    float x0, y0, x1, y1, ar;
    conv_box(ab[j], x0, y0, x1, y1, ar);
    sxy[j] = make_float4(x0, y0, x1, y1);
  }
  if (t < 32) {
    float x0, y0, x1, y1, ar;
    conv_box(gt[(size_t)b * G_N + half * 32 + t], x0, y0, x1, y1, ar);
    sg[0][t] = x0; sg[1][t] = y0; sg[2][t] = x1; sg[3][t] = y1; sg[4][t] = ar;
  }
  __syncthreads();

  u32 m = 0;   // bit k: anchor base+64k+lane has iou>=0.7 vs any of this thread's gts
  for (int gp = wave; gp < 8; gp += 4) {
    const int gi = gp * 4;
    const float g0x0 = sg[0][gi],   g0y0 = sg[1][gi],   g0x1 = sg[2][gi],   g0y1 = sg[3][gi],   g0a = sg[4][gi];
    const float g1x0 = sg[0][gi+1], g1y0 = sg[1][gi+1], g1x1 = sg[2][gi+1], g1y1 = sg[3][gi+1], g1a = sg[4][gi+1];
    const float g2x0 = sg[0][gi+2], g2y0 = sg[1][gi+2], g2x1 = sg[2][gi+2], g2y1 = sg[3][gi+2], g2a = sg[4][gi+2];
    const float g3x0 = sg[0][gi+3], g3y0 = sg[1][gi+3], g3x1 = sg[2][gi+3], g3y1 = sg[3][gi+3], g3a = sg[4][gi+3];

    // ---- pass 1: approx per-gt top-4 values (no div, no index, no branch) ----
    u32 q0[4] = {0,0,0,0}, q1[4] = {0,0,0,0}, q2[4] = {0,0,0,0}, q3[4] = {0,0,0,0};
    for (int j = lane; j < acnt; j += 64) {
      float4 x = sxy[j];
      float aarea = (x.z - x.x) * (x.w - x.y);
      float i0, u0, i1, u1, i2, u2, i3, u3;
      iou_parts(x.x, x.y, x.z, x.w, aarea, g0x0, g0y0, g0x1, g0y1, g0a, i0, u0);
      iou_parts(x.x, x.y, x.z, x.w, aarea, g1x0, g1y0, g1x1, g1y1, g1a, i1, u1);
      iou_parts(x.x, x.y, x.z, x.w, aarea, g2x0, g2y0, g2x1, g2y1, g2a, i2, u2);
      iou_parts(x.x, x.y, x.z, x.w, aarea, g3x0, g3y0, g3x1, g3y1, g3a, i3, u3);
      ins4_val(q0, __float_as_uint(i0 * __builtin_amdgcn_rcpf(u0)));
      ins4_val(q1, __float_as_uint(i1 * __builtin_amdgcn_rcpf(u1)));
      ins4_val(q2, __float_as_uint(i2 * __builtin_amdgcn_rcpf(u2)));
      ins4_val(q3, __float_as_uint(i3 * __builtin_amdgcn_rcpf(u3)));
    }
    wave_merge_top4_u32(q0);
    wave_merge_top4_u32(q1);
    wave_merge_top4_u32(q2);
    wave_merge_top4_u32(q3);
    // wave-uniform Q4 with 16-ulp rcp slack, capped by (0.7f - 8ulp)
    u32 Q40 = __shfl(q0[3], 0), Q41 = __shfl(q1[3], 0);
    u32 Q42 = __shfl(q2[3], 0), Q43 = __shfl(q3[3], 0);
    const u32 L7 = 0x3F333333u - 8u;   // 0.7f bits - 8 ulp
    float t0 = screen_thresh(min(Q40 > 16u ? Q40 - 16u : 0u, L7));
    float t1 = screen_thresh(min(Q41 > 16u ? Q41 - 16u : 0u, L7));
    float t2 = screen_thresh(min(Q42 > 16u ? Q42 - 16u : 0u, L7));
    float t3 = screen_thresh(min(Q43 > 16u ? Q43 - 16u : 0u, L7));

    // ---- pass 2: screened exact top-4 + >=0.7 bits ----
    u64 T0[4] = {0,0,0,0}, T1[4] = {0,0,0,0}, T2[4] = {0,0,0,0}, T3[4] = {0,0,0,0};
    u32 h0 = 0, h1 = 0, h2 = 0, h3 = 0;
    u32 bit = 1u;
    for (int j = lane; j < acnt; j += 64, bit <<= 1) {
      float4 x = sxy[j];
      float aarea = (x.z - x.x) * (x.w - x.y);
      float i0, u0, i1, u1, i2, u2, i3, u3;
      iou_parts(x.x, x.y, x.z, x.w, aarea, g0x0, g0y0, g0x1, g0y1, g0a, i0, u0);
      iou_parts(x.x, x.y, x.z, x.w, aarea, g1x0, g1y0, g1x1, g1y1, g1a, i1, u1);
      iou_parts(x.x, x.y, x.z, x.w, aarea, g2x0, g2y0, g2x1, g2y1, g2a, i2, u2);
      iou_parts(x.x, x.y, x.z, x.w, aarea, g3x0, g3y0, g3x1, g3y1, g3a, i3, u3);
      u32 ni = ~(u32)(base + j);
      bool s0 = (i0 >= t0 * u0), s1 = (i1 >= t1 * u1);
      bool s2 = (i2 >= t2 * u2), s3 = (i3 >= t3 * u3);
      if (__ballot(s0)) {
        float v = 0.0f;
        if (s0) { v = i0 / u0; if (v >= 0.7f) m |= bit; }
        u32 vb = __float_as_uint(v);
        bool ins = s0 && (vb >= h0);
        if (__ballot(ins)) {
          if (ins) top4_insert(T0, ((u64)vb << 32) | (u64)ni);
          h0 = (u32)(T0[3] >> 32);
        }
      }
      if (__ballot(s1)) {
        float v = 0.0f;
        if (s1) { v = i1 / u1; if (v >= 0.7f) m |= bit; }
        u32 vb = __float_as_uint(v);
        bool ins = s1 && (vb >= h1);
        if (__ballot(ins)) {
          if (ins) top4_insert(T1, ((u64)vb << 32) | (u64)ni);
          h1 = (u32)(T1[3] >> 32);
        }
      }
      if (__ballot(s2)) {
        float v = 0.0f;
        if (s2) { v = i2 / u2; if (v >= 0.7f) m |= bit; }
        u32 vb = __float_as_uint(v);
        bool ins = s2 && (vb >= h2);
        if (__ballot(ins)) {
          if (ins) top4_insert(T2, ((u64)vb << 32) | (u64)ni);
          h2 = (u32)(T2[3] >> 32);
        }
      }
      if (__ballot(s3)) {
        float v = 0.0f;
        if (s3) { v = i3 / u3; if (v >= 0.7f) m |= bit; }
        u32 vb = __float_as_uint(v);
        bool ins = s3 && (vb >= h3);
        if (__ballot(ins)) {
          if (ins) top4_insert(T3, ((u64)vb << 32) | (u64)ni);
          h3 = (u32)(T3[3] >> 32);
        }
      }
    }
    wave_merge_top4(T0);
    wave_merge_top4(T1);
    wave_merge_top4(T2);
    wave_merge_top4(T3);
    if (lane == 0) {
      const int g = half * 32 + gi;
      u64* dst = partial + (((size_t)b * NS + s) * G_N + g) * 4;
      #pragma unroll
      for (int k = 0; k < 4; k++) {
        dst[k] = T0[k]; dst[4 + k] = T1[k]; dst[8 + k] = T2[k]; dst[12 + k] = T3[k];
      }
    }
  }

  wm[t] = m;
  __syncthreads();
  if (wave == 0) {
    u32 mc = wm[lane] | wm[64 + lane] | wm[128 + lane] | wm[192 + lane];
    u64* posH = (half ? posB : posA) + (size_t)b * NWORD + s * WPS;
    for (int k = 0; k < WPS; k++) {
      u64 bal = __ballot((mc >> k) & 1u);
      if (lane == 0) posH[k] = bal;    // plain store — every word covered exactly once
    }
  }
}

// ---------------- Kernel 2: merge partials -> top4; lq anchors -> posA ----------------
__launch_bounds__(64)
__global__ void k_top4_merge(const u64* __restrict__ partial, u64* __restrict__ top4,
                             u64* __restrict__ posA) {
  const int b = blockIdx.y, g = blockIdx.x, lane = threadIdx.x;
  const u64* pb = partial + ((size_t)b * NS * G_N + g) * 4;
  u64 keys[7];                       // NS*4 = 392 -> <= 7 per lane
  int nk = 0;
  for (int i = lane; i < NS * 4; i += 64)
    keys[nk++] = pb[(size_t)(i >> 2) * (G_N * 4) + (i & 3)];
  u64 top[4] = {0ull, 0ull, 0ull, 0ull};
  for (int q = 0; q < nk; q++) top4_insert(top, keys[q]);
  wave_merge_top4(top);
  if (lane == 0) {
    u64* dst = top4 + ((size_t)b * G_N + g) * 4;
    #pragma unroll
    for (int k = 0; k < 4; k++) dst[k] = top[k];
  }
  // low-quality matches: every partial entry whose value bits == hq bits.
  u32 hqb = (u32)(__shfl(top[0], 0) >> 32);
  for (int q = 0; q < nk; q++) {
    u64 key = keys[q];
    u32 aidx = ~(u32)key;
    if ((u32)(key >> 32) == hqb && aidx < A_N)
      atomicOr(&posA[(size_t)b * NWORD + (aidx >> 6)], 1ull << (aidx & 63));
  }
}

// ---------------- Kernel 3: zero hist (aliases dead partial; must run post-merge) ----------------
__launch_bounds__(256)
__global__ void k_zero(u32* __restrict__ hist) {
  int i = blockIdx.x * 256 + threadIdx.x;
  if (i < B_IMG * 4096) hist[i] = 0;
}

// ---------------- Kernel 4: word-parallel npos + global hist (cold: atomics OK) ----------------
// grid (13, B): thread handles word blockIdx.x*256 + t.
__launch_bounds__(256)
__global__ void k_hist(const u64* __restrict__ posA, const u64* __restrict__ posB,
                       u32* __restrict__ npos, u32* __restrict__ hist) {
  const int b = blockIdx.y;
  const int i = blockIdx.x * 256 + threadIdx.x;
  u32 k0, k1; image_key(b, k0, k1);
  u32 c = 0;
  if (i < NWORD) {
    u64 w = posA[(size_t)b * NWORD + i] | posB[(size_t)b * NWORD + i];
    c = (u32)__popcll(w);
    while (w) {
      int bit = __ffsll((long long)w) - 1; w &= w - 1;
      u32 a = (u32)(i * 64 + bit);
      atomicAdd(&hist[b * 4096 + (rbits_for(k0, k1, a) >> 20)], 1u);
    }
  }
  #pragma unroll
  for (int off = 32; off >= 1; off >>= 1) c += __shfl_xor(c, off);
  if ((threadIdx.x & 63) == 0 && c) atomicAdd(&npos[b], c);
}

// ---------------- Kernel 5: local bin selection + collect fine candidates ----------------
// grid (NS, B).
__launch_bounds__(256)
__global__ void k_collect(const u64* __restrict__ posA, const u64* __restrict__ posB,
                          const u32* __restrict__ npos, const u32* __restrict__ hist,
                          int2* __restrict__ binsel,
                          u32* __restrict__ fine, u32* __restrict__ fcnt) {
  const int b = blockIdx.y;
  const int t = threadIdx.x;
  __shared__ u32 red[256];
  __shared__ int sbin;

  const u32* hb = hist + b * 4096;
  u32 local = 0;
  for (int j = 0; j < 16; j++) local += hb[t * 16 + j];
  red[t] = local;
  __syncthreads();
  if (t == 0) {
    if (npos[b] <= MAX_POS) {
      sbin = -1;
      binsel[b] = make_int2(-1, 0);          // duplicate identical writes across blocks
    } else {
      u32 cum = 0; int chunk = 0;
      for (int i = 0; i < 256; i++) {
        if (cum + red[i] >= MAX_POS) { chunk = i; break; }
        cum += red[i];
      }
      int tb = chunk * 16; u32 before = cum;
      for (int j = 0; j < 16; j++) {
        u32 h = hb[chunk * 16 + j];
        if (before + h >= MAX_POS) { tb = chunk * 16 + j; break; }
        before += h;
      }
      sbin = tb;
      binsel[b] = make_int2(tb, (int)before);
    }
  }
  __syncthreads();
  const int stb = sbin;
  if (stb < 0) return;

  u32 k0, k1; image_key(b, k0, k1);
  const int a0 = blockIdx.x * AS;
  const u64* pa = posA + (size_t)b * NWORD;
  const u64* pb = posB + (size_t)b * NWORD;
  for (int j = t; j < AS; j += 256) {
    int a = a0 + j;
    if (a >= A_N) break;
    if (!(((pa[a >> 6] | pb[a >> 6]) >> (a & 63)) & 1ull)) continue;
    u32 rb = rbits_for(k0, k1, (u32)a);
    if ((int)(rb >> 20) != stb) continue;
    u32 idx = atomicAdd(&fcnt[b], 1u);
    if (idx < FINE_CAP) fine[b * FINE_CAP + idx] = (((rb >> 9) & 0x7FFu) << 18) | (u32)a;
  }
}

// ---------------- Kernel 6: local Tstar + per-gt counts of selected ----------------
// grid (NS, B).
__launch_bounds__(256)
__global__ void k_count(const float4* __restrict__ anchors, const float4* __restrict__ gt,
                        const u64* __restrict__ posA, const u64* __restrict__ posB,
                        const int2* __restrict__ binsel, const u32* __restrict__ fine,
                        const u32* __restrict__ fcnt, u32* __restrict__ cnt) {
  const int b = blockIdx.y;
  const int t = threadIdx.x;
  __shared__ float sg[5][64];
  __shared__ u64 sT;

  if (t < 64) {
    float x0, y0, x1, y1, ar;
    conv_box(gt[(size_t)b * G_N + t], x0, y0, x1, y1, ar);
    sg[0][t] = x0; sg[1][t] = y0; sg[2][t] = x1; sg[3][t] = y1; sg[4][t] = ar;
    // wave 0: compute Tstar locally (binary search over the small fine list)
    int2 bs = binsel[b];
    u64 T = ~0ull;
    if (bs.x >= 0) {
      const int m = min((int)fcnt[b], FINE_CAP);
      const u32 need = (u32)(MAX_POS - bs.y);   // >= 1
      const u32* fb = fine + b * FINE_CAP;
      u32 lo = 0, hi = (1u << 29) - 1;
      while (lo < hi) {
        u32 mid = lo + ((hi - lo) >> 1);
        u32 c = 0;
        for (int j = t; j < m; j += 64) c += (fb[j] <= mid) ? 1u : 0u;
        #pragma unroll
        for (int off = 32; off >= 1; off >>= 1) c += __shfl_xor(c, off);
        if (c >= need) hi = mid; else lo = mid + 1;   // uniform across wave
      }
      T = ((u64)(u32)bs.x << 29) | (u64)lo;   // 41-bit threshold
    }
    if (t == 0) sT = T;
  }
  __syncthreads();

  u32 k0, k1; image_key(b, k0, k1);
  const u64 T = sT;
  const int a0 = blockIdx.x * AS;
  const u64* pa = posA + (size_t)b * NWORD;
  const u64* pb = posB + (size_t)b * NWORD;
  const float4* ab = anchors + (size_t)b * A_N;
  for (int j = t; j < AS; j += 256) {
    int a = a0 + j;
    if (a >= A_N) break;
    if (!(((pa[a >> 6] | pb[a >> 6]) >> (a & 63)) & 1ull)) continue;
    if (T != ~0ull) {
      u32 rb = rbits_for(k0, k1, (u32)a);
      if (((((u64)(rb >> 9)) << 18) | (u64)(u32)a) > T) continue;
    }
    float ax0, ay0, ax1, ay1, aar;
    conv_box(ab[a], ax0, ay0, ax1, ay1, aar);
    float bv = -1.0f; int g0 = 0;
    for (int g = 0; g < 64; g++) {
      float v = iou_pair(ax0, ay0, ax1, ay1, aar,
                         sg[0][g], sg[1][g], sg[2][g], sg[3][g], sg[4][g]);
      if (v > bv) { bv = v; g0 = g; }   // strict > = first max (jnp.argmax)
    }
    atomicAdd(&cnt[b * G_N + g0], 1u);
  }
}

// ---------------- Kernel 7: output ----------------
__launch_bounds__(64)
__global__ void k_out(const u64* __restrict__ top4, const u32* __restrict__ cnt,
                      float* __restrict__ out, int sec) {
  const int b = blockIdx.x;
  const int g = threadIdx.x;   // 64 threads
  const u32 c = min(cnt[b * G_N + g], (u32)K_TOP);
  const u64* t4 = top4 + ((size_t)b * G_N + g) * 4;
  #pragma unroll
  for (int k = 0; k < 4; k++) {
    u64 key = t4[k];
    u32 fb = (u32)(key >> 32);
    u32 aidx = ~(u32)key;
    bool valid = (u32)k < c;
    int o = b * (G_N * K_TOP) + g * K_TOP + k;
    out[0 * sec + o] = valid ? (float)aidx : -1.0f;          // pr_inds
    out[1 * sec + o] = valid ? (float)g : -1.0f;             // gt_inds
    out[2 * sec + o] = valid ? 1.0f : 0.0f;                  // valid mask
    out[3 * sec + o] = valid ? __uint_as_float(fb) : 0.0f;   // topk ious
  }
}

extern "C" void kernel_launch(void* const* d_in, const int* in_sizes, int n_in,
                              void* d_out, int out_size, void* d_ws, size_t ws_size,
                              hipStream_t stream) {
  const float4* anchors = (const float4*)d_in[0];  // [B, A, 4] cxcywh
  const float4* gt      = (const float4*)d_in[1];  // [B, G, 4] cxcywh
  float* out = (float*)d_out;                      // 4 x [B, G*K] concatenated

  // Layout — IDENTICAL EXTENT to the R5/R7-proven 2,025,536 B:
  //   top4    @ 0          (16,384)
  //   partial @ 16,384     (8*98*64*32 = 1,605,632) — dead after k_top4_merge;
  //     aliases (written only in dispatches >= 3):
  //       fine   @ 16,384    (131,072)  [k_collect]
  //       hist   @ 147,456   (131,072)  [zeroed by k_zero post-merge]
  //       binsel @ 278,528   (64)       [k_collect]
  //   posA    @ 1,622,016  (200,704)  [fully ballot-stored — no init]
  //   posB    @ 1,822,720  (200,704)  [fully ballot-stored — no init]
  //   small   @ 2,023,424  (2,112): npos(32) fcnt(32) cnt(2,048)
  //            [zeroed by k_top4_part s==0 blocks]
  char* ws = (char*)d_ws;
  u64*  top4    = (u64*)(ws);
  u64*  partial = (u64*)(ws + 16384);
  u32*  fine    = (u32*)(ws + 16384);
  u32*  hist    = (u32*)(ws + 147456);
  int2* binsel  = (int2*)(ws + 278528);
  u64*  posA    = (u64*)(ws + 1622016);
  u64*  posB    = (u64*)(ws + 1822720);
  u32*  npos    = (u32*)(ws + 2023424);
  u32*  fcnt    = (u32*)(ws + 2023456);
  u32*  cnt     = (u32*)(ws + 2023488);

  int sec = out_size / 4;  // 2048 = B*G*K

  k_top4_part <<<dim3(NS, B_IMG * 2), 256, 0, stream>>>(anchors, gt, partial, posA, posB,
                                                        npos, fcnt, cnt);
  k_top4_merge<<<dim3(G_N, B_IMG), 64, 0, stream>>>(partial, top4, posA);
  k_zero      <<<dim3(128), 256, 0, stream>>>(hist);
  k_hist      <<<dim3(13, B_IMG), 256, 0, stream>>>(posA, posB, npos, hist);
  k_collect   <<<dim3(NS, B_IMG), 256, 0, stream>>>(posA, posB, npos, hist, binsel, fine, fcnt);
  k_count     <<<dim3(NS, B_IMG), 256, 0, stream>>>(anchors, gt, posA, posB, binsel, fine, fcnt, cnt);
  k_out       <<<dim3(B_IMG), 64, 0, stream>>>(top4, cnt, out, sec);
}